// Round 7
// baseline (482.663 us; speedup 1.0000x reference)
//
#include <hip/hip_runtime.h>
#include <math.h>

#define NCL 10
#define DM 512
#define NH 8
#define DK 64
#define NB 8
#define SL 2048
#define LK 228
#define UF 100
#define KP_PER_B (NH*LK*DK)     // 116736
#define KP_TOT (NB*KP_PER_B)    // 933888
#define NROWS (NB*LK*UF)        // 182400
#define POOL2_BLOCKS 8192       // 2*NB*DM channels, one per block

typedef __bf16 bf16_t;
typedef __attribute__((ext_vector_type(2))) __bf16 bf16x2;
typedef __attribute__((ext_vector_type(8))) __bf16 bf16x8;
typedef __attribute__((ext_vector_type(4))) float f32x4;

__device__ __forceinline__ float gelu_f(float x) {
    return 0.5f * x * (1.f + erff(x * 0.70710678118654752f));
}

// ------------- kernel 1: max-pool K,V, LDS-staged coalesced ------------------
// One block per (kv, b, c) channel; stage 2048-float row via float4, max from
// LDS. Tail blocks: W1 -> bf16 TRANSPOSED prep (W1b holds W1^T [40][512] bf16
// for the MFMA mlp: W1bT[n*512+c] = Wq1[c*40+n]) + acc init.
__global__ void k_pool(const float* __restrict__ K, const float* __restrict__ V,
                       float* __restrict__ Kp, float* __restrict__ Vp,
                       const float* __restrict__ Wq1, bf16_t* __restrict__ W1b,
                       float* __restrict__ acc) {
    int bid = blockIdx.x;
    int tid = threadIdx.x;
    if (bid >= POOL2_BLOCKS) {
        int i = (bid - POOL2_BLOCKS) * 256 + tid;
        if (i < 512 * 40) {
            int c = i / 40;
            int n = i - c * 40;
            W1b[n * 512 + c] = (bf16_t)Wq1[i];
        }
        if (bid == POOL2_BLOCKS && tid < 4) acc[tid] = 0.f;
        return;
    }
    int kv = bid >> 12;          // 0 = K, 1 = V
    int e0 = bid & 4095;         // b*512 + c
    int b = e0 >> 9;
    int c = e0 & 511;
    const float* src = kv ? V : K;
    float* dst = kv ? Vp : Kp;
    __shared__ float buf[2048];
    const float* base = src + (size_t)e0 * 2048;
    #pragma unroll
    for (int i = 0; i < 2; ++i) {
        int i4 = (tid + i * 256) << 2;
        *(float4*)&buf[i4] = *(const float4*)&base[i4];
    }
    __syncthreads();
    if (tid < LK) {
        int p0 = tid * 9 - 4;
        float mx = -3.4e38f;
        #pragma unroll
        for (int j = 0; j < 9; ++j) {
            int p = p0 + j;
            if (p >= 0 && p < 2048) mx = fmaxf(mx, buf[p]);
        }
        dst[b * KP_PER_B + c * LK + tid] = mx;
    }
}

// ------------- kernel 2: MFMA q-MLP ------------------------------------------
// Dense-MFMA replacement for the latency-bound scalar version (R0-R5: ~98us,
// VALUBusy 26%, HBM 0.6%). Per (b,l): h = X[100x512] @ W1[512x40], X cell
// (m,c) nonzero iff t=(512m+c)%100 >= 100-b, s=t-99+b, r=(512m+c)/100,
// val=Kp[s][l*512+r]. K-loop: 16 chunks of 32; dense A[100][32] build (one
// pass), 16x16x32 bf16 MFMA, fragment patterns verbatim from verified k_attn:
//   A-frag: lane(ln,qd) = A[row=ln][cols qd*8..+7]; D: row=qd*4+r, col=ln.
// M-tiles 7 (tile 6 rows 100-111: A reads stray into hT LDS -- valid
// addresses, garbage only in D rows >=100 which are discarded; MFMA D-rows
// depend only on matching A-rows). N-tiles 3 (W1T rows 40-47 zero-padded).
// Waves: w0..w2 own M-tiles {w,w+4}, w3 owns {3}.
// ROUND-6 BUG FIXED: W1T staging previously covered only 32 of 64 16B-units
// per 512-col row -> cols 256..511 uninitialized -> NaN. Now idx<48*64.
// LDS: W1T bf16[48][520] @0 (49920) | A bf16[100][40] @49920 (8000) |
//      hT f32[100][44] @57920 (17600) | stats f32[112] @75520 -> 75968 B,
//      2 blocks/CU. launch_bounds(256,2): weak cap, no forced-spill (R1/R4).
__global__ __launch_bounds__(256, 2) void k_mlp(
        const float* __restrict__ Kp, const bf16_t* __restrict__ W1b,
        const float* __restrict__ bq1,
        const float* __restrict__ Wq2, const float* __restrict__ bq2,
        float* __restrict__ mu_g, float* __restrict__ centers_g,
        float* __restrict__ acc_g) {
    __shared__ __align__(16) char smem[75968];
    bf16_t* W1T  = (bf16_t*)smem;                // [48][520]
    bf16_t* A    = (bf16_t*)(smem + 49920);      // [100][40], cols 0..31 used
    float*  hT   = (float*)(smem + 57920);       // [100][44]
    float*  stats= (float*)(smem + 75520);       // [0..9]=total [10..109]=S [110]=lp

    int tid = threadIdx.x;
    int bl = blockIdx.x;          // 0..1823
    int b = bl / LK;
    int l = bl % LK;

    int lane = tid & 63;
    int wid = tid >> 6;
    int ln = lane & 15;
    int qd = lane >> 4;

    // stage W1T rows 0..39 from global W1b (=W1^T [40][512] bf16), zero 40..47
    // 48 rows x 64 16-byte units (512 bf16 = 1024 B per row)
    for (int idx = tid; idx < 48 * 64; idx += 256) {
        int n = idx >> 6;
        int c16 = idx & 63;           // 16-byte unit (8 bf16)
        float4 v;
        if (n < 40)
            v = *(const float4*)((const char*)W1b + n * 1024 + c16 * 16);
        else
            v = make_float4(0.f, 0.f, 0.f, 0.f);
        *(float4*)((char*)W1T + n * 1040 + c16 * 16) = v;
    }
    if (tid < 111) stats[tid] = 0.f;

    f32x4 acc0[3], acc1[3];
    #pragma unroll
    for (int nt = 0; nt < 3; ++nt) { acc0[nt] = (f32x4)(0.f); acc1[nt] = (f32x4)(0.f); }
    const int mt0 = wid;
    const int mt1 = wid + 4;
    const bool has1 = (wid < 3);
    const int tmin = 100 - b;     // cell nonzero iff t >= tmin (b=0: never)
    const float* Kpl = Kp + l * 512;

    __syncthreads();

    for (int kc = 0; kc < 16; ++kc) {
        int c0 = kc * 32;
        // dense A build: one pass, every cell written
        for (int idx = tid; idx < 3200; idx += 256) {
            int m = idx >> 5;
            int cc = idx & 31;
            int g = (m << 9) + c0 + cc;
            int q = g / 100;          // = r
            int t = g - q * 100;
            float val = 0.f;
            if (t >= tmin) {
                int s = t - 99 + b;   // 1..b
                val = Kpl[s * KP_PER_B + q];
            }
            A[m * 40 + cc] = (bf16_t)val;
        }
        __syncthreads();
        // MFMA: A-frag row = mt*16+ln, cols qd*8..+7 (chunk-local)
        bf16x8 bfr[3];
        #pragma unroll
        for (int nt = 0; nt < 3; ++nt)
            bfr[nt] = *(const bf16x8*)&W1T[(nt * 16 + ln) * 520 + c0 + qd * 8];
        bf16x8 a0 = *(const bf16x8*)&A[(mt0 * 16 + ln) * 40 + qd * 8];
        #pragma unroll
        for (int nt = 0; nt < 3; ++nt)
            acc0[nt] = __builtin_amdgcn_mfma_f32_16x16x32_bf16(a0, bfr[nt], acc0[nt], 0, 0, 0);
        if (has1) {
            bf16x8 a1 = *(const bf16x8*)&A[(mt1 * 16 + ln) * 40 + qd * 8];
            #pragma unroll
            for (int nt = 0; nt < 3; ++nt)
                acc1[nt] = __builtin_amdgcn_mfma_f32_16x16x32_bf16(a1, bfr[nt], acc1[nt], 0, 0, 0);
        }
        __syncthreads();
    }

    // epilogue: gelu(h + bq1) -> hT (D mapping: row=qd*4+r, col=ln, as k_attn)
    #pragma unroll
    for (int nt = 0; nt < 3; ++nt) {
        int n = nt * 16 + ln;
        if (n < 40) {
            float bn = bq1[n];
            #pragma unroll
            for (int r = 0; r < 4; ++r) {
                int m = mt0 * 16 + qd * 4 + r;
                if (m < 100) hT[m * 44 + n] = gelu_f(acc0[nt][r] + bn);
            }
            if (has1) {
                #pragma unroll
                for (int r = 0; r < 4; ++r) {
                    int m = mt1 * 16 + qd * 4 + r;
                    if (m < 100) hT[m * 44 + n] = gelu_f(acc1[nt][r] + bn);
                }
            }
        }
    }
    __syncthreads();

    // ---- UNCHANGED verified tail (layer2 + softmax + stats) ----
    float* total_l = stats;
    float* S_l = stats + 10;
    float* lp_acc = stats + 110;

    if (tid < 100) {
        int row = tid;
        float g[40];
        #pragma unroll
        for (int j4 = 0; j4 < 10; ++j4) {
            float4 gv = *(const float4*)&hT[row * 44 + j4 * 4];
            g[j4 * 4 + 0] = gv.x; g[j4 * 4 + 1] = gv.y;
            g[j4 * 4 + 2] = gv.z; g[j4 * 4 + 3] = gv.w;
        }
        float out[10];
        #pragma unroll
        for (int c = 0; c < 10; ++c) out[c] = bq2[c];
        #pragma unroll
        for (int j = 0; j < 40; ++j) {
            float gj = g[j];
            #pragma unroll
            for (int c = 0; c < 10; ++c)
                out[c] = fmaf(gj, Wq2[j * 10 + c], out[c]);
        }
        float m = out[0]; int am = 0;
        #pragma unroll
        for (int c = 1; c < 10; ++c)
            if (out[c] > m) { m = out[c]; am = c; }
        float e[10], s = 0.f;
        #pragma unroll
        for (int c = 0; c < 10; ++c) { e[c] = expf(out[c] - m); s += e[c]; }
        float inv = 1.f / s;
        float cq[10], s1 = 0.f;
        #pragma unroll
        for (int c = 0; c < 10; ++c) { cq[c] = e[c] * inv; s1 += cq[c]; }
        float mean = s1 * 0.1f;
        float var = 0.f;
        #pragma unroll
        for (int c = 0; c < 10; ++c) { float d = cq[c] - mean; var += d * d; }
        float sd = sqrtf(var / 9.f);
        float sp = log1pf(expf(sd));             // softplus(std)
        float lp = -logf(sp) - 0.91893853320467274f;  // ((x-mu)/sigma)^2 ~ 1e-16
        mu_g[bl * 100 + row] = mean;
        atomicAdd(lp_acc, lp);
        #pragma unroll
        for (int c = 0; c < 10; ++c) {
            atomicAdd(&total_l[c], cq[c]);
            atomicAdd(&S_l[am * 10 + c], cq[c]);
        }
    }
    __syncthreads();
    if (tid == 0) atomicAdd(&acc_g[0], lp_acc[0]);
    if (tid < 100) {
        centers_g[bl * 100 + tid] = (total_l[tid % 10] - S_l[tid]) * 0.01f;
    }
}

// ------------- kernel 3: cross-entropy over l axis (+ fused final loss) -----
__global__ void k_ce(const float* __restrict__ mu_g, float* __restrict__ acc_g,
                     float* __restrict__ outp) {
    int bid = blockIdx.x;     // 800 = (b,u)
    int b = bid / 100;
    int u = bid % 100;
    int lane = threadIdx.x;   // 64
    float v[4];
    #pragma unroll
    for (int t = 0; t < 4; ++t) {
        int l = lane + t * 64;
        v[t] = (l < LK) ? mu_g[(b * LK + l) * 100 + u] : -3.4e38f;
    }
    float m = fmaxf(fmaxf(v[0], v[1]), fmaxf(v[2], v[3]));
    for (int o = 32; o > 0; o >>= 1) m = fmaxf(m, __shfl_xor(m, o, 64));
    float se = 0.f;
    #pragma unroll
    for (int t = 0; t < 4; ++t) {
        int l = lane + t * 64;
        if (l < LK) se += expf(v[t] - m);
    }
    for (int o = 32; o > 0; o >>= 1) se += __shfl_xor(se, o, 64);
    float lse = m + logf(se);
    float dot = 0.f;
    #pragma unroll
    for (int t = 0; t < 4; ++t) {
        int l = lane + t * 64;
        if (l < LK) dot += v[t] * (v[t] - lse);
    }
    for (int o = 32; o > 0; o >>= 1) dot += __shfl_xor(dot, o, 64);
    if (lane == 0) {
        atomicAdd(&acc_g[1], -dot * (1.f / 800.f));
        __threadfence();
        unsigned int old = atomicAdd((unsigned int*)&acc_g[2], 1u);
        if (old == 799u) {
            __threadfence();
            outp[8388608] = -(acc_g[0] * (1.f / (float)NROWS)) + acc_g[1];
        }
    }
}

// ------------- kernel 4: fused proj_back(gelu) + reshape-sum over clusters --
__global__ void k_ccs(const float* __restrict__ centers_g,
                      const float* __restrict__ Wp, const float* __restrict__ bp,
                      float* __restrict__ ccs) {
    int tid = blockIdx.x * 256 + threadIdx.x;
    if (tid >= KP_TOT) return;
    int k2d2 = tid % (LK * DK);
    int bh = tid / (LK * DK);
    float s = 0.f;
    #pragma unroll
    for (int i2 = 0; i2 < 10; ++i2) {
        int t2 = bh * 145920 + i2 * 14592 + k2d2;   // flat index into cc [10,8,228,512]
        int i = t2 / 933888;
        int r1 = t2 % 933888;
        int bs = r1 / 116736;
        int r2 = r1 % 116736;
        int ls = r2 / 512;
        int mm = r2 % 512;
        const float* cen = centers_g + (bs * LK + ls) * 100 + i * 10;
        float val = bp[mm];
        #pragma unroll
        for (int c = 0; c < 10; ++c)
            val = fmaf(cen[c], Wp[c * 512 + mm], val);
        s += gelu_f(val);
    }
    ccs[tid] = s;
}

// ------------- kernel 5: MFMA flash attention (228 keys, chunks of 64) ------
#define QT 128
__global__ __launch_bounds__(256, 3) void k_attn(
        const float* __restrict__ Q, const float* __restrict__ ccs,
        const float* __restrict__ Vp, float* __restrict__ outp) {
    __shared__ __align__(16) char smem[36864];
    bf16_t* Kl = (bf16_t*)(smem);
    bf16_t* Vt = (bf16_t*)(smem + 9216);
    bf16_t* Pl = (bf16_t*)(smem + 18432);

    int tid = threadIdx.x;
    int wid = tid >> 6;
    int lane = tid & 63;
    int ln = lane & 15;
    int qd = lane >> 4;
    int bid = blockIdx.x;        // 1024
    int bh = bid >> 4;           // b*8+h
    int qt = bid & 15;
    int qbase = qt * QT;

    const float* Qbh = Q + (size_t)bh * SL * DK;
    const float* Kbh = ccs + (size_t)bh * LK * DK;
    const float* Vbh = Vp + (size_t)bh * LK * DK;

    for (int s = tid; s < QT * 32; s += 256) {
        int r = s >> 5;
        int c2 = s & 31;
        float2 v = *(const float2*)&Qbh[(size_t)(qbase + r) * DK + c2 * 2];
        *(bf16x2*)&Pl[r * 72 + c2 * 2] = (bf16x2){(bf16_t)v.x, (bf16_t)v.y};
    }
    __syncthreads();
    bf16x8 qf[2][2];
    #pragma unroll
    for (int mt = 0; mt < 2; ++mt)
        #pragma unroll
        for (int ks = 0; ks < 2; ++ks)
            qf[mt][ks] = *(const bf16x8*)&Pl[(wid * 32 + mt * 16 + ln) * 72 + ks * 32 + qd * 8];

    f32x4 acc_o[2][4];
    float mrow[2][4], lrow[2][4];
    #pragma unroll
    for (int mt = 0; mt < 2; ++mt)
        #pragma unroll
        for (int t = 0; t < 4; ++t) {
            acc_o[mt][t] = (f32x4)(0.f);
            mrow[mt][t] = -3.0e38f;
            lrow[mt][t] = 0.f;
        }

    for (int ch = 0; ch < 4; ++ch) {
        int k0 = ch * 64;
        __syncthreads();
        for (int s = tid; s < 64 * 32; s += 256) {
            int kk = s >> 5;
            int c2 = s & 31;
            int key = k0 + kk;
            float2 v = (key < LK) ? *(const float2*)&Kbh[(size_t)key * DK + c2 * 2]
                                  : make_float2(0.f, 0.f);
            *(bf16x2*)&Kl[kk * 72 + c2 * 2] = (bf16x2){(bf16_t)v.x, (bf16_t)v.y};
        }
        for (int s = tid; s < 64 * 16; s += 256) {
            int kk = s >> 4;
            int c4 = s & 15;
            int key = k0 + kk;
            float4 v = (key < LK) ? *(const float4*)&Vbh[(size_t)key * DK + c4 * 4]
                                  : make_float4(0.f, 0.f, 0.f, 0.f);
            Vt[(c4 * 4 + 0) * 72 + kk] = (bf16_t)v.x;
            Vt[(c4 * 4 + 1) * 72 + kk] = (bf16_t)v.y;
            Vt[(c4 * 4 + 2) * 72 + kk] = (bf16_t)v.z;
            Vt[(c4 * 4 + 3) * 72 + kk] = (bf16_t)v.w;
        }
        __syncthreads();

        f32x4 accs[2][4];
        #pragma unroll
        for (int mt = 0; mt < 2; ++mt)
            #pragma unroll
            for (int nt = 0; nt < 4; ++nt) accs[mt][nt] = (f32x4)(0.f);
        #pragma unroll
        for (int ks = 0; ks < 2; ++ks) {
            #pragma unroll
            for (int nt = 0; nt < 4; ++nt) {
                bf16x8 bf = *(const bf16x8*)&Kl[(nt * 16 + ln) * 72 + ks * 32 + qd * 8];
                #pragma unroll
                for (int mt = 0; mt < 2; ++mt)
                    accs[mt][nt] = __builtin_amdgcn_mfma_f32_16x16x32_bf16(qf[mt][ks], bf, accs[mt][nt], 0, 0, 0);
            }
        }

        #pragma unroll
        for (int mt = 0; mt < 2; ++mt) {
            #pragma unroll
            for (int r = 0; r < 4; ++r) {
                float sv[4];
                #pragma unroll
                for (int nt = 0; nt < 4; ++nt) {
                    float s = accs[mt][nt][r] * 0.125f;
                    int key = k0 + nt * 16 + ln;
                    sv[nt] = (key < LK) ? s : -3.0e38f;
                }
                float rmax = fmaxf(fmaxf(sv[0], sv[1]), fmaxf(sv[2], sv[3]));
                #pragma unroll
                for (int o = 1; o < 16; o <<= 1)
                    rmax = fmaxf(rmax, __shfl_xor(rmax, o, 64));
                float mold = mrow[mt][r];
                float mnew = fmaxf(mold, rmax);
                float alpha = __expf(mold - mnew);
                float p[4], psum = 0.f;
                #pragma unroll
                for (int nt = 0; nt < 4; ++nt) {
                    p[nt] = __expf(sv[nt] - mnew);
                    psum += p[nt];
                }
                #pragma unroll
                for (int o = 1; o < 16; o <<= 1)
                    psum += __shfl_xor(psum, o, 64);
                lrow[mt][r] = lrow[mt][r] * alpha + psum;
                mrow[mt][r] = mnew;
                #pragma unroll
                for (int ntv = 0; ntv < 4; ++ntv)
                    acc_o[mt][ntv][r] *= alpha;
                int prow = (wid * 32 + mt * 16 + qd * 4 + r) * 72;
                #pragma unroll
                for (int nt = 0; nt < 4; ++nt)
                    Pl[prow + nt * 16 + ln] = (bf16_t)p[nt];
            }
        }

        #pragma unroll
        for (int ks = 0; ks < 2; ++ks) {
            bf16x8 pa[2];
            #pragma unroll
            for (int mt = 0; mt < 2; ++mt)
                pa[mt] = *(const bf16x8*)&Pl[(wid * 32 + mt * 16 + ln) * 72 + ks * 32 + qd * 8];
            #pragma unroll
            for (int ntv = 0; ntv < 4; ++ntv) {
                bf16x8 vb = *(const bf16x8*)&Vt[(ntv * 16 + ln) * 72 + ks * 32 + qd * 8];
                #pragma unroll
                for (int mt = 0; mt < 2; ++mt)
                    acc_o[mt][ntv] = __builtin_amdgcn_mfma_f32_16x16x32_bf16(pa[mt], vb, acc_o[mt][ntv], 0, 0, 0);
            }
        }
    }

    #pragma unroll
    for (int mt = 0; mt < 2; ++mt) {
        #pragma unroll
        for (int r = 0; r < 4; ++r) {
            float inv = 1.f / lrow[mt][r];
            int q_idx = qbase + wid * 32 + mt * 16 + qd * 4 + r;
            float* orow = outp + ((size_t)bh * SL + q_idx) * DK;
            #pragma unroll
            for (int ntv = 0; ntv < 4; ++ntv)
                orow[ntv * 16 + ln] = acc_o[mt][ntv][r] * inv;
        }
    }
}

extern "C" void kernel_launch(void* const* d_in, const int* in_sizes, int n_in,
                              void* d_out, int out_size, void* d_ws, size_t ws_size,
                              hipStream_t stream) {
    const float* Q   = (const float*)d_in[0];
    const float* K   = (const float*)d_in[1];
    const float* V   = (const float*)d_in[2];
    const float* Wq1 = (const float*)d_in[7];
    const float* bq1 = (const float*)d_in[8];
    const float* Wq2 = (const float*)d_in[9];
    const float* bq2 = (const float*)d_in[10];
    const float* Wp  = (const float*)d_in[11];
    const float* bp  = (const float*)d_in[12];
    float* out = (float*)d_out;

    float* ws      = (float*)d_ws;
    float* Kp      = ws;                 // 933888
    float* Vp      = ws + 933888;        // 933888
    float* mu      = ws + 1867776;       // 182400
    float* centers = ws + 2050176;       // 182400
    float* ccs     = ws + 2232576;       // 933888
    float* acc     = ws + 3166464;       // 4 (acc[2] doubles as uint counter)
    bf16_t* W1b    = (bf16_t*)(ws + 3166468);  // W1^T [40][512] bf16 = 40960 B

    // pool (+ W1^T bf16 prep + acc init) -> mlp -> ccs -> ce(+final) -> attn
    k_pool<<<POOL2_BLOCKS + 80, 256, 0, stream>>>(K, V, Kp, Vp, Wq1, W1b, acc);
    k_mlp<<<NB * LK, 256, 0, stream>>>(Kp, W1b, bq1, Wq2, bq2, mu, centers, acc);
    k_ccs<<<(KP_TOT + 255) / 256, 256, 0, stream>>>(centers, Wp, bp, ccs);
    k_ce<<<NB * 100, 64, 0, stream>>>(mu, acc, out);
    k_attn<<<NB * NH * (SL / QT), 256, 0, stream>>>(Q, ccs, Vp, out);
}

// Round 8
// 331.311 us; speedup vs baseline: 1.4568x; 1.4568x over previous
//
#include <hip/hip_runtime.h>
#include <math.h>

#define NCL 10
#define DM 512
#define NH 8
#define DK 64
#define NB 8
#define SL 2048
#define LK 228
#define UF 100
#define KP_PER_B (NH*LK*DK)     // 116736
#define KP_TOT (NB*KP_PER_B)    // 933888
#define NROWS (NB*LK*UF)        // 182400
#define POOL2_BLOCKS 8192       // 2*NB*DM channels, one per block

typedef __bf16 bf16_t;
typedef __attribute__((ext_vector_type(2))) __bf16 bf16x2;
typedef __attribute__((ext_vector_type(8))) __bf16 bf16x8;
typedef __attribute__((ext_vector_type(4))) float f32x4;

__device__ __forceinline__ float gelu_f(float x) {
    return 0.5f * x * (1.f + erff(x * 0.70710678118654752f));
}

// ------------- kernel 1: max-pool K,V, LDS-staged coalesced ------------------
// One block per (kv, b, c) channel; stage 2048-float row via float4, max from
// LDS (stride 9 coprime to 32 banks -> conflict-free). Writes contiguous.
// Tail blocks: W1 -> bf16 prep (row-major [512][40], as the scalar mlp needs)
// + acc init.
__global__ void k_pool(const float* __restrict__ K, const float* __restrict__ V,
                       float* __restrict__ Kp, float* __restrict__ Vp,
                       const float* __restrict__ Wq1, bf16_t* __restrict__ W1b,
                       float* __restrict__ acc) {
    int bid = blockIdx.x;
    int tid = threadIdx.x;
    if (bid >= POOL2_BLOCKS) {
        int i = (bid - POOL2_BLOCKS) * 256 + tid;
        if (i < 512 * 40) W1b[i] = (bf16_t)Wq1[i];
        if (bid == POOL2_BLOCKS && tid < 4) acc[tid] = 0.f;
        return;
    }
    int kv = bid >> 12;          // 0 = K, 1 = V
    int e0 = bid & 4095;         // b*512 + c
    int b = e0 >> 9;
    int c = e0 & 511;
    const float* src = kv ? V : K;
    float* dst = kv ? Vp : Kp;
    __shared__ float buf[2048];
    const float* base = src + (size_t)e0 * 2048;
    #pragma unroll
    for (int i = 0; i < 2; ++i) {
        int i4 = (tid + i * 256) << 2;
        *(float4*)&buf[i4] = *(const float4*)&base[i4];
    }
    __syncthreads();
    if (tid < LK) {
        int p0 = tid * 9 - 4;
        float mx = -3.4e38f;
        #pragma unroll
        for (int j = 0; j < 9; ++j) {
            int p = p0 + j;
            if (p >= 0 && p < 2048) mx = fmaxf(mx, buf[p]);
        }
        dst[b * KP_PER_B + c * LK + tid] = mx;
    }
}

// ------------- kernel 2: sparse q-MLP, b-specialized unrolled layer 1 --------
// R5-VERIFIED INNER CODE (98.5us, VGPR 52, FETCH 3.4MB, zero spill). Eight
// experiments (R1-R4, R6-R7: fused-L2, preload arrays, 512thr, MFMA) all
// regressed via codegen or staging overhead. DO NOT TOUCH the inner stream.
// Only two surviving, individually-verified tweaks applied:
//  (a) b-interleave: b=bid&7, l=bid>>3 (and/shift replaces div/mod; heavy
//      b=7 blocks spread through dispatch; correctness-verified R1/R2/R4).
//  (b) Sstf row-0 drop: compile-time base-offset constants only
//      (correctness-verified R3). LDS 34432 -> 32384 B < 32KiB => HW
//      residency 5 blocks/CU (was 4): +25% waves on a latency-bound kernel.
//      launch_bounds stays (256,4) -- hint affects regalloc only; HW
//      residency follows actual LDS/VGPR.
// LDS: Sstf f32[7][512] @0 (14336) | hT f32[100][44] @14336 (17600) |
//      stats f32[111] @31936 -> 32384 B.
template<int B>
__device__ __forceinline__ void layer1(int tid, const bf16_t* __restrict__ W1b,
                                       const float* __restrict__ Sstf,
                                       float* __restrict__ hT) {
    #pragma unroll 1
    for (int k = 0; k < 2; ++k) {
        int vt = tid + (k << 8);
        if (vt < 500) {
            int m = vt / 5;
            int h8 = vt - m * 5;            // 0..4 -> cols h8*8..h8*8+7
            int bm = (12 * m) % 100;
            float h[8];
            #pragma unroll
            for (int i = 0; i < 8; ++i) h[i] = 0.f;
            #pragma unroll
            for (int s = 1; s <= B; ++s) {
                const int t = 99 - B + s;
                int d0 = t - bm; if (d0 < 0) d0 += 100;
                int r0 = ((m << 9) + d0 - t) / 100;   // exact division
                const float* srow = &Sstf[(s - 1) << 9];
                #pragma unroll
                for (int j = 0; j < 6; ++j) {
                    int c = d0 + j * 100;
                    if (j < 5 || c < 512) {
                        float v = srow[r0 + j];
                        bf16x8 w = *(const bf16x8*)&W1b[c * 40 + h8 * 8];
                        #pragma unroll
                        for (int i = 0; i < 8; ++i)
                            h[i] = fmaf(v, (float)w[i], h[i]);
                    }
                }
            }
            #pragma unroll
            for (int i = 0; i < 8; ++i) hT[m * 44 + h8 * 8 + i] = h[i];
        }
    }
}

__global__ __launch_bounds__(256, 4) void k_mlp(
        const float* __restrict__ Kp, const bf16_t* __restrict__ W1b,
        const float* __restrict__ bq1,
        const float* __restrict__ Wq2, const float* __restrict__ bq2,
        float* __restrict__ mu_g, float* __restrict__ centers_g,
        float* __restrict__ acc_g) {
    __shared__ __align__(16) char smem[32384];
    float* Sstf  = (float*)smem;                 // [7][512], row (bk-1)
    float* hT    = (float*)(smem + 14336);       // [100][44]
    float* stats = (float*)(smem + 31936);       // [0..9]=total [10..109]=S [110]=lp

    int tid = threadIdx.x;
    int bid = blockIdx.x;          // 0..1823, b interleaved for load balance
    int b = bid & 7;
    int l = bid >> 3;              // 0..227
    int bl = b * LK + l;           // output row index

    // stage Sstf rows for bk=1..b: coalesced float4 copy from Kp
    for (int s4 = tid; s4 < 128 * b; s4 += 256) {
        int bk = (s4 >> 7) + 1;
        int r4 = (s4 & 127) << 2;
        *(float4*)&Sstf[((bk - 1) << 9) + r4] =
            *(const float4*)&Kp[bk * KP_PER_B + l * 512 + r4];
    }
    if (tid < 111) stats[tid] = 0.f;
    if (b == 0) {
        for (int i = tid; i < 4400; i += 256) hT[i] = 0.f;
    }
    __syncthreads();

    switch (b) {
        case 1: layer1<1>(tid, W1b, Sstf, hT); break;
        case 2: layer1<2>(tid, W1b, Sstf, hT); break;
        case 3: layer1<3>(tid, W1b, Sstf, hT); break;
        case 4: layer1<4>(tid, W1b, Sstf, hT); break;
        case 5: layer1<5>(tid, W1b, Sstf, hT); break;
        case 6: layer1<6>(tid, W1b, Sstf, hT); break;
        case 7: layer1<7>(tid, W1b, Sstf, hT); break;
        default: break;
    }
    __syncthreads();

    // gelu(+bias) in place, distributed
    for (int i = tid; i < 4000; i += 256) {
        int row = i / 40;
        int j = i - row * 40;
        hT[row * 44 + j] = gelu_f(hT[row * 44 + j] + bq1[j]);
    }
    __syncthreads();

    float* total_l = stats;
    float* S_l = stats + 10;
    float* lp_acc = stats + 110;

    if (tid < 100) {
        int row = tid;
        float g[40];
        #pragma unroll
        for (int j4 = 0; j4 < 10; ++j4) {
            float4 gv = *(const float4*)&hT[row * 44 + j4 * 4];
            g[j4 * 4 + 0] = gv.x; g[j4 * 4 + 1] = gv.y;
            g[j4 * 4 + 2] = gv.z; g[j4 * 4 + 3] = gv.w;
        }
        float out[10];
        #pragma unroll
        for (int c = 0; c < 10; ++c) out[c] = bq2[c];
        #pragma unroll
        for (int j = 0; j < 40; ++j) {
            float gj = g[j];
            #pragma unroll
            for (int c = 0; c < 10; ++c)
                out[c] = fmaf(gj, Wq2[j * 10 + c], out[c]);
        }
        float m = out[0]; int am = 0;
        #pragma unroll
        for (int c = 1; c < 10; ++c)
            if (out[c] > m) { m = out[c]; am = c; }
        float e[10], s = 0.f;
        #pragma unroll
        for (int c = 0; c < 10; ++c) { e[c] = expf(out[c] - m); s += e[c]; }
        float inv = 1.f / s;
        float cq[10], s1 = 0.f;
        #pragma unroll
        for (int c = 0; c < 10; ++c) { cq[c] = e[c] * inv; s1 += cq[c]; }
        float mean = s1 * 0.1f;
        float var = 0.f;
        #pragma unroll
        for (int c = 0; c < 10; ++c) { float d = cq[c] - mean; var += d * d; }
        float sd = sqrtf(var / 9.f);
        float sp = log1pf(expf(sd));             // softplus(std)
        float lp = -logf(sp) - 0.91893853320467274f;  // ((x-mu)/sigma)^2 ~ 1e-16
        mu_g[bl * 100 + row] = mean;
        atomicAdd(lp_acc, lp);
        #pragma unroll
        for (int c = 0; c < 10; ++c) {
            atomicAdd(&total_l[c], cq[c]);
            atomicAdd(&S_l[am * 10 + c], cq[c]);
        }
    }
    __syncthreads();
    if (tid == 0) atomicAdd(&acc_g[0], lp_acc[0]);
    if (tid < 100) {
        centers_g[bl * 100 + tid] = (total_l[tid % 10] - S_l[tid]) * 0.01f;
    }
}

// ------------- kernel 3: cross-entropy over l axis (+ fused final loss) -----
__global__ void k_ce(const float* __restrict__ mu_g, float* __restrict__ acc_g,
                     float* __restrict__ outp) {
    int bid = blockIdx.x;     // 800 = (b,u)
    int b = bid / 100;
    int u = bid % 100;
    int lane = threadIdx.x;   // 64
    float v[4];
    #pragma unroll
    for (int t = 0; t < 4; ++t) {
        int l = lane + t * 64;
        v[t] = (l < LK) ? mu_g[(b * LK + l) * 100 + u] : -3.4e38f;
    }
    float m = fmaxf(fmaxf(v[0], v[1]), fmaxf(v[2], v[3]));
    for (int o = 32; o > 0; o >>= 1) m = fmaxf(m, __shfl_xor(m, o, 64));
    float se = 0.f;
    #pragma unroll
    for (int t = 0; t < 4; ++t) {
        int l = lane + t * 64;
        if (l < LK) se += expf(v[t] - m);
    }
    for (int o = 32; o > 0; o >>= 1) se += __shfl_xor(se, o, 64);
    float lse = m + logf(se);
    float dot = 0.f;
    #pragma unroll
    for (int t = 0; t < 4; ++t) {
        int l = lane + t * 64;
        if (l < LK) dot += v[t] * (v[t] - lse);
    }
    for (int o = 32; o > 0; o >>= 1) dot += __shfl_xor(dot, o, 64);
    if (lane == 0) {
        atomicAdd(&acc_g[1], -dot * (1.f / 800.f));
        __threadfence();
        unsigned int old = atomicAdd((unsigned int*)&acc_g[2], 1u);
        if (old == 799u) {
            __threadfence();
            outp[8388608] = -(acc_g[0] * (1.f / (float)NROWS)) + acc_g[1];
        }
    }
}

// ------------- kernel 4: fused proj_back(gelu) + reshape-sum over clusters --
__global__ void k_ccs(const float* __restrict__ centers_g,
                      const float* __restrict__ Wp, const float* __restrict__ bp,
                      float* __restrict__ ccs) {
    int tid = blockIdx.x * 256 + threadIdx.x;
    if (tid >= KP_TOT) return;
    int k2d2 = tid % (LK * DK);
    int bh = tid / (LK * DK);
    float s = 0.f;
    #pragma unroll
    for (int i2 = 0; i2 < 10; ++i2) {
        int t2 = bh * 145920 + i2 * 14592 + k2d2;   // flat index into cc [10,8,228,512]
        int i = t2 / 933888;
        int r1 = t2 % 933888;
        int bs = r1 / 116736;
        int r2 = r1 % 116736;
        int ls = r2 / 512;
        int mm = r2 % 512;
        const float* cen = centers_g + (bs * LK + ls) * 100 + i * 10;
        float val = bp[mm];
        #pragma unroll
        for (int c = 0; c < 10; ++c)
            val = fmaf(cen[c], Wp[c * 512 + mm], val);
        s += gelu_f(val);
    }
    ccs[tid] = s;
}

// ------------- kernel 5: MFMA flash attention (228 keys, chunks of 64) ------
#define QT 128
__global__ __launch_bounds__(256, 3) void k_attn(
        const float* __restrict__ Q, const float* __restrict__ ccs,
        const float* __restrict__ Vp, float* __restrict__ outp) {
    __shared__ __align__(16) char smem[36864];
    bf16_t* Kl = (bf16_t*)(smem);
    bf16_t* Vt = (bf16_t*)(smem + 9216);
    bf16_t* Pl = (bf16_t*)(smem + 18432);

    int tid = threadIdx.x;
    int wid = tid >> 6;
    int lane = tid & 63;
    int ln = lane & 15;
    int qd = lane >> 4;
    int bid = blockIdx.x;        // 1024
    int bh = bid >> 4;           // b*8+h
    int qt = bid & 15;
    int qbase = qt * QT;

    const float* Qbh = Q + (size_t)bh * SL * DK;
    const float* Kbh = ccs + (size_t)bh * LK * DK;
    const float* Vbh = Vp + (size_t)bh * LK * DK;

    for (int s = tid; s < QT * 32; s += 256) {
        int r = s >> 5;
        int c2 = s & 31;
        float2 v = *(const float2*)&Qbh[(size_t)(qbase + r) * DK + c2 * 2];
        *(bf16x2*)&Pl[r * 72 + c2 * 2] = (bf16x2){(bf16_t)v.x, (bf16_t)v.y};
    }
    __syncthreads();
    bf16x8 qf[2][2];
    #pragma unroll
    for (int mt = 0; mt < 2; ++mt)
        #pragma unroll
        for (int ks = 0; ks < 2; ++ks)
            qf[mt][ks] = *(const bf16x8*)&Pl[(wid * 32 + mt * 16 + ln) * 72 + ks * 32 + qd * 8];

    f32x4 acc_o[2][4];
    float mrow[2][4], lrow[2][4];
    #pragma unroll
    for (int mt = 0; mt < 2; ++mt)
        #pragma unroll
        for (int t = 0; t < 4; ++t) {
            acc_o[mt][t] = (f32x4)(0.f);
            mrow[mt][t] = -3.0e38f;
            lrow[mt][t] = 0.f;
        }

    for (int ch = 0; ch < 4; ++ch) {
        int k0 = ch * 64;
        __syncthreads();
        for (int s = tid; s < 64 * 32; s += 256) {
            int kk = s >> 5;
            int c2 = s & 31;
            int key = k0 + kk;
            float2 v = (key < LK) ? *(const float2*)&Kbh[(size_t)key * DK + c2 * 2]
                                  : make_float2(0.f, 0.f);
            *(bf16x2*)&Kl[kk * 72 + c2 * 2] = (bf16x2){(bf16_t)v.x, (bf16_t)v.y};
        }
        for (int s = tid; s < 64 * 16; s += 256) {
            int kk = s >> 4;
            int c4 = s & 15;
            int key = k0 + kk;
            float4 v = (key < LK) ? *(const float4*)&Vbh[(size_t)key * DK + c4 * 4]
                                  : make_float4(0.f, 0.f, 0.f, 0.f);
            Vt[(c4 * 4 + 0) * 72 + kk] = (bf16_t)v.x;
            Vt[(c4 * 4 + 1) * 72 + kk] = (bf16_t)v.y;
            Vt[(c4 * 4 + 2) * 72 + kk] = (bf16_t)v.z;
            Vt[(c4 * 4 + 3) * 72 + kk] = (bf16_t)v.w;
        }
        __syncthreads();

        f32x4 accs[2][4];
        #pragma unroll
        for (int mt = 0; mt < 2; ++mt)
            #pragma unroll
            for (int nt = 0; nt < 4; ++nt) accs[mt][nt] = (f32x4)(0.f);
        #pragma unroll
        for (int ks = 0; ks < 2; ++ks) {
            #pragma unroll
            for (int nt = 0; nt < 4; ++nt) {
                bf16x8 bf = *(const bf16x8*)&Kl[(nt * 16 + ln) * 72 + ks * 32 + qd * 8];
                #pragma unroll
                for (int mt = 0; mt < 2; ++mt)
                    accs[mt][nt] = __builtin_amdgcn_mfma_f32_16x16x32_bf16(qf[mt][ks], bf, accs[mt][nt], 0, 0, 0);
            }
        }

        #pragma unroll
        for (int mt = 0; mt < 2; ++mt) {
            #pragma unroll
            for (int r = 0; r < 4; ++r) {
                float sv[4];
                #pragma unroll
                for (int nt = 0; nt < 4; ++nt) {
                    float s = accs[mt][nt][r] * 0.125f;
                    int key = k0 + nt * 16 + ln;
                    sv[nt] = (key < LK) ? s : -3.0e38f;
                }
                float rmax = fmaxf(fmaxf(sv[0], sv[1]), fmaxf(sv[2], sv[3]));
                #pragma unroll
                for (int o = 1; o < 16; o <<= 1)
                    rmax = fmaxf(rmax, __shfl_xor(rmax, o, 64));
                float mold = mrow[mt][r];
                float mnew = fmaxf(mold, rmax);
                float alpha = __expf(mold - mnew);
                float p[4], psum = 0.f;
                #pragma unroll
                for (int nt = 0; nt < 4; ++nt) {
                    p[nt] = __expf(sv[nt] - mnew);
                    psum += p[nt];
                }
                #pragma unroll
                for (int o = 1; o < 16; o <<= 1)
                    psum += __shfl_xor(psum, o, 64);
                lrow[mt][r] = lrow[mt][r] * alpha + psum;
                mrow[mt][r] = mnew;
                #pragma unroll
                for (int ntv = 0; ntv < 4; ++ntv)
                    acc_o[mt][ntv][r] *= alpha;
                int prow = (wid * 32 + mt * 16 + qd * 4 + r) * 72;
                #pragma unroll
                for (int nt = 0; nt < 4; ++nt)
                    Pl[prow + nt * 16 + ln] = (bf16_t)p[nt];
            }
        }

        #pragma unroll
        for (int ks = 0; ks < 2; ++ks) {
            bf16x8 pa[2];
            #pragma unroll
            for (int mt = 0; mt < 2; ++mt)
                pa[mt] = *(const bf16x8*)&Pl[(wid * 32 + mt * 16 + ln) * 72 + ks * 32 + qd * 8];
            #pragma unroll
            for (int ntv = 0; ntv < 4; ++ntv) {
                bf16x8 vb = *(const bf16x8*)&Vt[(ntv * 16 + ln) * 72 + ks * 32 + qd * 8];
                #pragma unroll
                for (int mt = 0; mt < 2; ++mt)
                    acc_o[mt][ntv] = __builtin_amdgcn_mfma_f32_16x16x32_bf16(pa[mt], vb, acc_o[mt][ntv], 0, 0, 0);
            }
        }
    }

    #pragma unroll
    for (int mt = 0; mt < 2; ++mt) {
        #pragma unroll
        for (int r = 0; r < 4; ++r) {
            float inv = 1.f / lrow[mt][r];
            int q_idx = qbase + wid * 32 + mt * 16 + qd * 4 + r;
            float* orow = outp + ((size_t)bh * SL + q_idx) * DK;
            #pragma unroll
            for (int ntv = 0; ntv < 4; ++ntv)
                orow[ntv * 16 + ln] = acc_o[mt][ntv][r] * inv;
        }
    }
}

extern "C" void kernel_launch(void* const* d_in, const int* in_sizes, int n_in,
                              void* d_out, int out_size, void* d_ws, size_t ws_size,
                              hipStream_t stream) {
    const float* Q   = (const float*)d_in[0];
    const float* K   = (const float*)d_in[1];
    const float* V   = (const float*)d_in[2];
    const float* Wq1 = (const float*)d_in[7];
    const float* bq1 = (const float*)d_in[8];
    const float* Wq2 = (const float*)d_in[9];
    const float* bq2 = (const float*)d_in[10];
    const float* Wp  = (const float*)d_in[11];
    const float* bp  = (const float*)d_in[12];
    float* out = (float*)d_out;

    float* ws      = (float*)d_ws;
    float* Kp      = ws;                 // 933888
    float* Vp      = ws + 933888;        // 933888
    float* mu      = ws + 1867776;       // 182400
    float* centers = ws + 2050176;       // 182400
    float* ccs     = ws + 2232576;       // 933888
    float* acc     = ws + 3166464;       // 4 (acc[2] doubles as uint counter)
    bf16_t* W1b    = (bf16_t*)(ws + 3166468);  // 512*40 bf16 = 40960 B

    // pool (+ W1 bf16 prep + acc init) -> mlp -> ccs -> ce(+final) -> attn
    k_pool<<<POOL2_BLOCKS + 80, 256, 0, stream>>>(K, V, Kp, Vp, Wq1, W1b, acc);
    k_mlp<<<NB * LK, 256, 0, stream>>>(Kp, W1b, bq1, Wq2, bq2, mu, centers, acc);
    k_ccs<<<(KP_TOT + 255) / 256, 256, 0, stream>>>(centers, Wp, bp, ccs);
    k_ce<<<NB * 100, 64, 0, stream>>>(mu, acc, out);
    k_attn<<<NB * NH * (SL / QT), 256, 0, stream>>>(Q, ccs, Vp, out);
}

// Round 9
// 324.654 us; speedup vs baseline: 1.4867x; 1.0205x over previous
//
#include <hip/hip_runtime.h>
#include <math.h>

#define NCL 10
#define DM 512
#define NH 8
#define DK 64
#define NB 8
#define SL 2048
#define LK 228
#define UF 100
#define KP_PER_B (NH*LK*DK)     // 116736
#define KP_TOT (NB*KP_PER_B)    // 933888
#define NROWS (NB*LK*UF)        // 182400
#define POOL2_BLOCKS 8192       // 2*NB*DM channels, one per block
#define KCCS_BLOCKS 3648        // KP_TOT/256
#define KCE_BLOCKS 200          // 800 (b,u) units, 4 per block

typedef __bf16 bf16_t;
typedef __attribute__((ext_vector_type(2))) __bf16 bf16x2;
typedef __attribute__((ext_vector_type(8))) __bf16 bf16x8;
typedef __attribute__((ext_vector_type(4))) float f32x4;

__device__ __forceinline__ float gelu_f(float x) {
    return 0.5f * x * (1.f + erff(x * 0.70710678118654752f));
}

// ------------- kernel 1: max-pool K,V, LDS-staged coalesced ------------------
// One block per (kv, b, c) channel; stage 2048-float row via float4, max from
// LDS (stride 9 coprime to 32 banks -> conflict-free). Writes contiguous.
// Tail blocks: W1 -> bf16 prep (row-major [512][40]) + acc init.
__global__ void k_pool(const float* __restrict__ K, const float* __restrict__ V,
                       float* __restrict__ Kp, float* __restrict__ Vp,
                       const float* __restrict__ Wq1, bf16_t* __restrict__ W1b,
                       float* __restrict__ acc) {
    int bid = blockIdx.x;
    int tid = threadIdx.x;
    if (bid >= POOL2_BLOCKS) {
        int i = (bid - POOL2_BLOCKS) * 256 + tid;
        if (i < 512 * 40) W1b[i] = (bf16_t)Wq1[i];
        if (bid == POOL2_BLOCKS && tid < 4) acc[tid] = 0.f;
        return;
    }
    int kv = bid >> 12;          // 0 = K, 1 = V
    int e0 = bid & 4095;         // b*512 + c
    int b = e0 >> 9;
    int c = e0 & 511;
    const float* src = kv ? V : K;
    float* dst = kv ? Vp : Kp;
    __shared__ float buf[2048];
    const float* base = src + (size_t)e0 * 2048;
    #pragma unroll
    for (int i = 0; i < 2; ++i) {
        int i4 = (tid + i * 256) << 2;
        *(float4*)&buf[i4] = *(const float4*)&base[i4];
    }
    __syncthreads();
    if (tid < LK) {
        int p0 = tid * 9 - 4;
        float mx = -3.4e38f;
        #pragma unroll
        for (int j = 0; j < 9; ++j) {
            int p = p0 + j;
            if (p >= 0 && p < 2048) mx = fmaxf(mx, buf[p]);
        }
        dst[b * KP_PER_B + c * LK + tid] = mx;
    }
}

// ------------- kernel 2: sparse q-MLP, b-specialized unrolled layer 1 --------
// FROZEN at the R8-verified state (~100us, VGPR 44, zero spill). Nine
// experiments showed the inner stream is a codegen knife-edge. Only change
// this round: mu written TRANSPOSED (mu[(b*100+u)*LK + l]) so k_ce reads
// coalesce -- tail-only store-address edit, layer1 untouched.
// LDS: Sstf f32[7][512] @0 (14336) | hT f32[100][44] @14336 (17600) |
//      stats f32[111] @31936 -> 32384 B.
template<int B>
__device__ __forceinline__ void layer1(int tid, const bf16_t* __restrict__ W1b,
                                       const float* __restrict__ Sstf,
                                       float* __restrict__ hT) {
    #pragma unroll 1
    for (int k = 0; k < 2; ++k) {
        int vt = tid + (k << 8);
        if (vt < 500) {
            int m = vt / 5;
            int h8 = vt - m * 5;            // 0..4 -> cols h8*8..h8*8+7
            int bm = (12 * m) % 100;
            float h[8];
            #pragma unroll
            for (int i = 0; i < 8; ++i) h[i] = 0.f;
            #pragma unroll
            for (int s = 1; s <= B; ++s) {
                const int t = 99 - B + s;
                int d0 = t - bm; if (d0 < 0) d0 += 100;
                int r0 = ((m << 9) + d0 - t) / 100;   // exact division
                const float* srow = &Sstf[(s - 1) << 9];
                #pragma unroll
                for (int j = 0; j < 6; ++j) {
                    int c = d0 + j * 100;
                    if (j < 5 || c < 512) {
                        float v = srow[r0 + j];
                        bf16x8 w = *(const bf16x8*)&W1b[c * 40 + h8 * 8];
                        #pragma unroll
                        for (int i = 0; i < 8; ++i)
                            h[i] = fmaf(v, (float)w[i], h[i]);
                    }
                }
            }
            #pragma unroll
            for (int i = 0; i < 8; ++i) hT[m * 44 + h8 * 8 + i] = h[i];
        }
    }
}

__global__ __launch_bounds__(256, 4) void k_mlp(
        const float* __restrict__ Kp, const bf16_t* __restrict__ W1b,
        const float* __restrict__ bq1,
        const float* __restrict__ Wq2, const float* __restrict__ bq2,
        float* __restrict__ mu_g, float* __restrict__ centers_g,
        float* __restrict__ acc_g) {
    __shared__ __align__(16) char smem[32384];
    float* Sstf  = (float*)smem;                 // [7][512], row (bk-1)
    float* hT    = (float*)(smem + 14336);       // [100][44]
    float* stats = (float*)(smem + 31936);       // [0..9]=total [10..109]=S [110]=lp

    int tid = threadIdx.x;
    int bid = blockIdx.x;          // 0..1823, b interleaved for load balance
    int b = bid & 7;
    int l = bid >> 3;              // 0..227
    int bl = b * LK + l;           // output row index

    // stage Sstf rows for bk=1..b: coalesced float4 copy from Kp
    for (int s4 = tid; s4 < 128 * b; s4 += 256) {
        int bk = (s4 >> 7) + 1;
        int r4 = (s4 & 127) << 2;
        *(float4*)&Sstf[((bk - 1) << 9) + r4] =
            *(const float4*)&Kp[bk * KP_PER_B + l * 512 + r4];
    }
    if (tid < 111) stats[tid] = 0.f;
    if (b == 0) {
        for (int i = tid; i < 4400; i += 256) hT[i] = 0.f;
    }
    __syncthreads();

    switch (b) {
        case 1: layer1<1>(tid, W1b, Sstf, hT); break;
        case 2: layer1<2>(tid, W1b, Sstf, hT); break;
        case 3: layer1<3>(tid, W1b, Sstf, hT); break;
        case 4: layer1<4>(tid, W1b, Sstf, hT); break;
        case 5: layer1<5>(tid, W1b, Sstf, hT); break;
        case 6: layer1<6>(tid, W1b, Sstf, hT); break;
        case 7: layer1<7>(tid, W1b, Sstf, hT); break;
        default: break;
    }
    __syncthreads();

    // gelu(+bias) in place, distributed
    for (int i = tid; i < 4000; i += 256) {
        int row = i / 40;
        int j = i - row * 40;
        hT[row * 44 + j] = gelu_f(hT[row * 44 + j] + bq1[j]);
    }
    __syncthreads();

    float* total_l = stats;
    float* S_l = stats + 10;
    float* lp_acc = stats + 110;

    if (tid < 100) {
        int row = tid;
        float g[40];
        #pragma unroll
        for (int j4 = 0; j4 < 10; ++j4) {
            float4 gv = *(const float4*)&hT[row * 44 + j4 * 4];
            g[j4 * 4 + 0] = gv.x; g[j4 * 4 + 1] = gv.y;
            g[j4 * 4 + 2] = gv.z; g[j4 * 4 + 3] = gv.w;
        }
        float out[10];
        #pragma unroll
        for (int c = 0; c < 10; ++c) out[c] = bq2[c];
        #pragma unroll
        for (int j = 0; j < 40; ++j) {
            float gj = g[j];
            #pragma unroll
            for (int c = 0; c < 10; ++c)
                out[c] = fmaf(gj, Wq2[j * 10 + c], out[c]);
        }
        float m = out[0]; int am = 0;
        #pragma unroll
        for (int c = 1; c < 10; ++c)
            if (out[c] > m) { m = out[c]; am = c; }
        float e[10], s = 0.f;
        #pragma unroll
        for (int c = 0; c < 10; ++c) { e[c] = expf(out[c] - m); s += e[c]; }
        float inv = 1.f / s;
        float cq[10], s1 = 0.f;
        #pragma unroll
        for (int c = 0; c < 10; ++c) { cq[c] = e[c] * inv; s1 += cq[c]; }
        float mean = s1 * 0.1f;
        float var = 0.f;
        #pragma unroll
        for (int c = 0; c < 10; ++c) { float d = cq[c] - mean; var += d * d; }
        float sd = sqrtf(var / 9.f);
        float sp = log1pf(expf(sd));             // softplus(std)
        float lp = -logf(sp) - 0.91893853320467274f;  // ((x-mu)/sigma)^2 ~ 1e-16
        mu_g[(b * 100 + row) * LK + l] = mean;   // TRANSPOSED for coalesced ce
        atomicAdd(lp_acc, lp);
        #pragma unroll
        for (int c = 0; c < 10; ++c) {
            atomicAdd(&total_l[c], cq[c]);
            atomicAdd(&S_l[am * 10 + c], cq[c]);
        }
    }
    __syncthreads();
    if (tid == 0) atomicAdd(&acc_g[0], lp_acc[0]);
    if (tid < 100) {
        centers_g[bl * 100 + tid] = (total_l[tid % 10] - S_l[tid]) * 0.01f;
    }
}

// ------------- kernel 3: fused [proj_back+reshape-sum] ++ [cross-entropy] ---
// Blocks 0..3647: ccs (933888 elements). Blocks 3648..3847: ce, 4 wave-units
// per block (800 (b,u) units). Independent ops -> merged for overlap + one
// fewer launch. ccs index math: all magic-divides reduced to shifts using
// LK*DK=14592, 933888=64*14592, 116736=8*14592 (exact; k2d2<14592 => no
// carries): i=J>>6, Jm=J&63, bs=Jm>>3, r2=(Jm&7)*14592+k2d2, ls=r2>>9,
// mm=r2&511 where J=bh*10+i2.
__global__ void k_ccs_ce(const float* __restrict__ centers_g,
                         const float* __restrict__ Wp, const float* __restrict__ bp,
                         float* __restrict__ ccs,
                         const float* __restrict__ mu_g, float* __restrict__ acc_g,
                         float* __restrict__ outp) {
    int bid = blockIdx.x;
    if (bid < KCCS_BLOCKS) {
        int tid = bid * 256 + threadIdx.x;
        int k2d2 = tid % (LK * DK);
        int bh = tid / (LK * DK);
        float s = 0.f;
        #pragma unroll
        for (int i2 = 0; i2 < 10; ++i2) {
            int J  = bh * 10 + i2;
            int i  = J >> 6;
            int Jm = J & 63;
            int bs = Jm >> 3;
            int r2 = (Jm & 7) * 14592 + k2d2;
            int ls = r2 >> 9;
            int mm = r2 & 511;
            const float* cen = centers_g + (bs * LK + ls) * 100 + i * 10;
            float val = bp[mm];
            #pragma unroll
            for (int c = 0; c < 10; ++c)
                val = fmaf(cen[c], Wp[c * 512 + mm], val);
            s += gelu_f(val);
        }
        ccs[tid] = s;
        return;
    }
    // ---- ce part: unit = (bid-KCCS)*4 + wave; reads mu^T coalesced ----
    int unit = (bid - KCCS_BLOCKS) * 4 + (threadIdx.x >> 6);
    int b = unit / 100;
    int u = unit % 100;
    int lane = threadIdx.x & 63;
    const float* murow = mu_g + (b * 100 + u) * LK;
    float v[4];
    #pragma unroll
    for (int t = 0; t < 4; ++t) {
        int l = lane + t * 64;
        v[t] = (l < LK) ? murow[l] : -3.4e38f;
    }
    float m = fmaxf(fmaxf(v[0], v[1]), fmaxf(v[2], v[3]));
    for (int o = 32; o > 0; o >>= 1) m = fmaxf(m, __shfl_xor(m, o, 64));
    float se = 0.f;
    #pragma unroll
    for (int t = 0; t < 4; ++t) {
        int l = lane + t * 64;
        if (l < LK) se += expf(v[t] - m);
    }
    for (int o = 32; o > 0; o >>= 1) se += __shfl_xor(se, o, 64);
    float lse = m + logf(se);
    float dot = 0.f;
    #pragma unroll
    for (int t = 0; t < 4; ++t) {
        int l = lane + t * 64;
        if (l < LK) dot += v[t] * (v[t] - lse);
    }
    for (int o = 32; o > 0; o >>= 1) dot += __shfl_xor(dot, o, 64);
    if (lane == 0) {
        atomicAdd(&acc_g[1], -dot * (1.f / 800.f));
        __threadfence();
        unsigned int old = atomicAdd((unsigned int*)&acc_g[2], 1u);
        if (old == 799u) {
            __threadfence();
            outp[8388608] = -(acc_g[0] * (1.f / (float)NROWS)) + acc_g[1];
        }
    }
}

// ------------- kernel 4: MFMA flash attention (228 keys, chunks of 64) ------
// Changes vs verified version: (a) 1/8 score scale folded into Q staging --
// power-of-2 scale commutes exactly with bf16 rounding, bit-identical;
// (b) launch_bounds (256,3)->(256,4): LDS 36864*4=147KB fits -> +33% waves.
#define QT 128
__global__ __launch_bounds__(256, 4) void k_attn(
        const float* __restrict__ Q, const float* __restrict__ ccs,
        const float* __restrict__ Vp, float* __restrict__ outp) {
    __shared__ __align__(16) char smem[36864];
    bf16_t* Kl = (bf16_t*)(smem);
    bf16_t* Vt = (bf16_t*)(smem + 9216);
    bf16_t* Pl = (bf16_t*)(smem + 18432);

    int tid = threadIdx.x;
    int wid = tid >> 6;
    int lane = tid & 63;
    int ln = lane & 15;
    int qd = lane >> 4;
    int bid = blockIdx.x;        // 1024
    int bh = bid >> 4;           // b*8+h
    int qt = bid & 15;
    int qbase = qt * QT;

    const float* Qbh = Q + (size_t)bh * SL * DK;
    const float* Kbh = ccs + (size_t)bh * LK * DK;
    const float* Vbh = Vp + (size_t)bh * LK * DK;

    for (int s = tid; s < QT * 32; s += 256) {
        int r = s >> 5;
        int c2 = s & 31;
        float2 v = *(const float2*)&Qbh[(size_t)(qbase + r) * DK + c2 * 2];
        *(bf16x2*)&Pl[r * 72 + c2 * 2] =
            (bf16x2){(bf16_t)(v.x * 0.125f), (bf16_t)(v.y * 0.125f)};
    }
    __syncthreads();
    bf16x8 qf[2][2];
    #pragma unroll
    for (int mt = 0; mt < 2; ++mt)
        #pragma unroll
        for (int ks = 0; ks < 2; ++ks)
            qf[mt][ks] = *(const bf16x8*)&Pl[(wid * 32 + mt * 16 + ln) * 72 + ks * 32 + qd * 8];

    f32x4 acc_o[2][4];
    float mrow[2][4], lrow[2][4];
    #pragma unroll
    for (int mt = 0; mt < 2; ++mt)
        #pragma unroll
        for (int t = 0; t < 4; ++t) {
            acc_o[mt][t] = (f32x4)(0.f);
            mrow[mt][t] = -3.0e38f;
            lrow[mt][t] = 0.f;
        }

    for (int ch = 0; ch < 4; ++ch) {
        int k0 = ch * 64;
        __syncthreads();
        for (int s = tid; s < 64 * 32; s += 256) {
            int kk = s >> 5;
            int c2 = s & 31;
            int key = k0 + kk;
            float2 v = (key < LK) ? *(const float2*)&Kbh[(size_t)key * DK + c2 * 2]
                                  : make_float2(0.f, 0.f);
            *(bf16x2*)&Kl[kk * 72 + c2 * 2] = (bf16x2){(bf16_t)v.x, (bf16_t)v.y};
        }
        for (int s = tid; s < 64 * 16; s += 256) {
            int kk = s >> 4;
            int c4 = s & 15;
            int key = k0 + kk;
            float4 v = (key < LK) ? *(const float4*)&Vbh[(size_t)key * DK + c4 * 4]
                                  : make_float4(0.f, 0.f, 0.f, 0.f);
            Vt[(c4 * 4 + 0) * 72 + kk] = (bf16_t)v.x;
            Vt[(c4 * 4 + 1) * 72 + kk] = (bf16_t)v.y;
            Vt[(c4 * 4 + 2) * 72 + kk] = (bf16_t)v.z;
            Vt[(c4 * 4 + 3) * 72 + kk] = (bf16_t)v.w;
        }
        __syncthreads();

        f32x4 accs[2][4];
        #pragma unroll
        for (int mt = 0; mt < 2; ++mt)
            #pragma unroll
            for (int nt = 0; nt < 4; ++nt) accs[mt][nt] = (f32x4)(0.f);
        #pragma unroll
        for (int ks = 0; ks < 2; ++ks) {
            #pragma unroll
            for (int nt = 0; nt < 4; ++nt) {
                bf16x8 bf = *(const bf16x8*)&Kl[(nt * 16 + ln) * 72 + ks * 32 + qd * 8];
                #pragma unroll
                for (int mt = 0; mt < 2; ++mt)
                    accs[mt][nt] = __builtin_amdgcn_mfma_f32_16x16x32_bf16(qf[mt][ks], bf, accs[mt][nt], 0, 0, 0);
            }
        }

        #pragma unroll
        for (int mt = 0; mt < 2; ++mt) {
            #pragma unroll
            for (int r = 0; r < 4; ++r) {
                float sv[4];
                #pragma unroll
                for (int nt = 0; nt < 4; ++nt) {
                    float s = accs[mt][nt][r];
                    int key = k0 + nt * 16 + ln;
                    sv[nt] = (key < LK) ? s : -3.0e38f;
                }
                float rmax = fmaxf(fmaxf(sv[0], sv[1]), fmaxf(sv[2], sv[3]));
                #pragma unroll
                for (int o = 1; o < 16; o <<= 1)
                    rmax = fmaxf(rmax, __shfl_xor(rmax, o, 64));
                float mold = mrow[mt][r];
                float mnew = fmaxf(mold, rmax);
                float alpha = __expf(mold - mnew);
                float p[4], psum = 0.f;
                #pragma unroll
                for (int nt = 0; nt < 4; ++nt) {
                    p[nt] = __expf(sv[nt] - mnew);
                    psum += p[nt];
                }
                #pragma unroll
                for (int o = 1; o < 16; o <<= 1)
                    psum += __shfl_xor(psum, o, 64);
                lrow[mt][r] = lrow[mt][r] * alpha + psum;
                mrow[mt][r] = mnew;
                #pragma unroll
                for (int ntv = 0; ntv < 4; ++ntv)
                    acc_o[mt][ntv][r] *= alpha;
                int prow = (wid * 32 + mt * 16 + qd * 4 + r) * 72;
                #pragma unroll
                for (int nt = 0; nt < 4; ++nt)
                    Pl[prow + nt * 16 + ln] = (bf16_t)p[nt];
            }
        }

        #pragma unroll
        for (int ks = 0; ks < 2; ++ks) {
            bf16x8 pa[2];
            #pragma unroll
            for (int mt = 0; mt < 2; ++mt)
                pa[mt] = *(const bf16x8*)&Pl[(wid * 32 + mt * 16 + ln) * 72 + ks * 32 + qd * 8];
            #pragma unroll
            for (int ntv = 0; ntv < 4; ++ntv) {
                bf16x8 vb = *(const bf16x8*)&Vt[(ntv * 16 + ln) * 72 + ks * 32 + qd * 8];
                #pragma unroll
                for (int mt = 0; mt < 2; ++mt)
                    acc_o[mt][ntv] = __builtin_amdgcn_mfma_f32_16x16x32_bf16(pa[mt], vb, acc_o[mt][ntv], 0, 0, 0);
            }
        }
    }

    #pragma unroll
    for (int mt = 0; mt < 2; ++mt) {
        #pragma unroll
        for (int r = 0; r < 4; ++r) {
            float inv = 1.f / lrow[mt][r];
            int q_idx = qbase + wid * 32 + mt * 16 + qd * 4 + r;
            float* orow = outp + ((size_t)bh * SL + q_idx) * DK;
            #pragma unroll
            for (int ntv = 0; ntv < 4; ++ntv)
                orow[ntv * 16 + ln] = acc_o[mt][ntv][r] * inv;
        }
    }
}

extern "C" void kernel_launch(void* const* d_in, const int* in_sizes, int n_in,
                              void* d_out, int out_size, void* d_ws, size_t ws_size,
                              hipStream_t stream) {
    const float* Q   = (const float*)d_in[0];
    const float* K   = (const float*)d_in[1];
    const float* V   = (const float*)d_in[2];
    const float* Wq1 = (const float*)d_in[7];
    const float* bq1 = (const float*)d_in[8];
    const float* Wq2 = (const float*)d_in[9];
    const float* bq2 = (const float*)d_in[10];
    const float* Wp  = (const float*)d_in[11];
    const float* bp  = (const float*)d_in[12];
    float* out = (float*)d_out;

    float* ws      = (float*)d_ws;
    float* Kp      = ws;                 // 933888
    float* Vp      = ws + 933888;        // 933888
    float* mu      = ws + 1867776;       // 182400 (transposed [800][228])
    float* centers = ws + 2050176;       // 182400
    float* ccs     = ws + 2232576;       // 933888
    float* acc     = ws + 3166464;       // 4 (acc[2] doubles as uint counter)
    bf16_t* W1b    = (bf16_t*)(ws + 3166468);  // 512*40 bf16 = 40960 B

    // pool (+ W1 prep + acc init) -> mlp -> [ccs ++ ce(+final)] -> attn
    k_pool<<<POOL2_BLOCKS + 80, 256, 0, stream>>>(K, V, Kp, Vp, Wq1, W1b, acc);
    k_mlp<<<NB * LK, 256, 0, stream>>>(Kp, W1b, bq1, Wq2, bq2, mu, centers, acc);
    k_ccs_ce<<<KCCS_BLOCKS + KCE_BLOCKS, 256, 0, stream>>>(centers, Wp, bp, ccs,
                                                           mu, acc, out);
    k_attn<<<NB * NH * (SL / QT), 256, 0, stream>>>(Q, ccs, Vp, out);
}

// Round 10
// 320.651 us; speedup vs baseline: 1.5053x; 1.0125x over previous
//
#include <hip/hip_runtime.h>
#include <math.h>

#define NCL 10
#define DM 512
#define NH 8
#define DK 64
#define NB 8
#define SL 2048
#define LK 228
#define UF 100
#define KP_PER_B (NH*LK*DK)     // 116736
#define KP_TOT (NB*KP_PER_B)    // 933888
#define NROWS (NB*LK*UF)        // 182400
#define POOL2_BLOCKS 8192       // 2*NB*DM channels, one per block
#define KCCS_BLOCKS 3648        // KP_TOT/256
#define KCE_BLOCKS 200          // 800 (b,u) units, 4 per block

typedef __bf16 bf16_t;
typedef __attribute__((ext_vector_type(2))) __bf16 bf16x2;
typedef __attribute__((ext_vector_type(4))) __bf16 bf16x4;
typedef __attribute__((ext_vector_type(8))) __bf16 bf16x8;
typedef __attribute__((ext_vector_type(4))) float f32x4;

__device__ __forceinline__ float gelu_f(float x) {
    return 0.5f * x * (1.f + erff(x * 0.70710678118654752f));
}

// ------------- kernel 1: max-pool K,V, LDS-staged coalesced ------------------
// One block per (kv, b, c) channel; stage 2048-float row via float4, max from
// LDS (stride 9 coprime to 32 banks -> conflict-free). K path writes f32 Kp
// (mlp needs f32); V path writes bf16 Vp (consumed ONLY by attn, which
// rounded to bf16 at staging anyway -> bit-identical, half the bytes).
// Tail blocks: W1 -> bf16 prep (row-major [512][40]) + acc init.
__global__ void k_pool(const float* __restrict__ K, const float* __restrict__ V,
                       float* __restrict__ Kp, bf16_t* __restrict__ Vpb,
                       const float* __restrict__ Wq1, bf16_t* __restrict__ W1b,
                       float* __restrict__ acc) {
    int bid = blockIdx.x;
    int tid = threadIdx.x;
    if (bid >= POOL2_BLOCKS) {
        int i = (bid - POOL2_BLOCKS) * 256 + tid;
        if (i < 512 * 40) W1b[i] = (bf16_t)Wq1[i];
        if (bid == POOL2_BLOCKS && tid < 4) acc[tid] = 0.f;
        return;
    }
    int kv = bid >> 12;          // 0 = K, 1 = V
    int e0 = bid & 4095;         // b*512 + c
    int b = e0 >> 9;
    int c = e0 & 511;
    const float* src = kv ? V : K;
    __shared__ float buf[2048];
    const float* base = src + (size_t)e0 * 2048;
    #pragma unroll
    for (int i = 0; i < 2; ++i) {
        int i4 = (tid + i * 256) << 2;
        *(float4*)&buf[i4] = *(const float4*)&base[i4];
    }
    __syncthreads();
    if (tid < LK) {
        int p0 = tid * 9 - 4;
        float mx = -3.4e38f;
        #pragma unroll
        for (int j = 0; j < 9; ++j) {
            int p = p0 + j;
            if (p >= 0 && p < 2048) mx = fmaxf(mx, buf[p]);
        }
        int e = b * KP_PER_B + c * LK + tid;
        if (kv) Vpb[e] = (bf16_t)mx;
        else    Kp[e]  = mx;
    }
}

// ------------- kernel 2: sparse q-MLP, b-specialized unrolled layer 1 --------
// FROZEN at the R8-verified state (~100us, VGPR 44, zero spill); R9's mu
// transpose cost +9.5us (scattered stores) and is REVERTED -- mu store is
// contiguous again; ce reads the strided layout (verified R0-R8).
// LDS: Sstf f32[7][512] @0 (14336) | hT f32[100][44] @14336 (17600) |
//      stats f32[111] @31936 -> 32384 B.
template<int B>
__device__ __forceinline__ void layer1(int tid, const bf16_t* __restrict__ W1b,
                                       const float* __restrict__ Sstf,
                                       float* __restrict__ hT) {
    #pragma unroll 1
    for (int k = 0; k < 2; ++k) {
        int vt = tid + (k << 8);
        if (vt < 500) {
            int m = vt / 5;
            int h8 = vt - m * 5;            // 0..4 -> cols h8*8..h8*8+7
            int bm = (12 * m) % 100;
            float h[8];
            #pragma unroll
            for (int i = 0; i < 8; ++i) h[i] = 0.f;
            #pragma unroll
            for (int s = 1; s <= B; ++s) {
                const int t = 99 - B + s;
                int d0 = t - bm; if (d0 < 0) d0 += 100;
                int r0 = ((m << 9) + d0 - t) / 100;   // exact division
                const float* srow = &Sstf[(s - 1) << 9];
                #pragma unroll
                for (int j = 0; j < 6; ++j) {
                    int c = d0 + j * 100;
                    if (j < 5 || c < 512) {
                        float v = srow[r0 + j];
                        bf16x8 w = *(const bf16x8*)&W1b[c * 40 + h8 * 8];
                        #pragma unroll
                        for (int i = 0; i < 8; ++i)
                            h[i] = fmaf(v, (float)w[i], h[i]);
                    }
                }
            }
            #pragma unroll
            for (int i = 0; i < 8; ++i) hT[m * 44 + h8 * 8 + i] = h[i];
        }
    }
}

__global__ __launch_bounds__(256, 4) void k_mlp(
        const float* __restrict__ Kp, const bf16_t* __restrict__ W1b,
        const float* __restrict__ bq1,
        const float* __restrict__ Wq2, const float* __restrict__ bq2,
        float* __restrict__ mu_g, float* __restrict__ centers_g,
        float* __restrict__ acc_g) {
    __shared__ __align__(16) char smem[32384];
    float* Sstf  = (float*)smem;                 // [7][512], row (bk-1)
    float* hT    = (float*)(smem + 14336);       // [100][44]
    float* stats = (float*)(smem + 31936);       // [0..9]=total [10..109]=S [110]=lp

    int tid = threadIdx.x;
    int bid = blockIdx.x;          // 0..1823, b interleaved for load balance
    int b = bid & 7;
    int l = bid >> 3;              // 0..227
    int bl = b * LK + l;           // output row index

    // stage Sstf rows for bk=1..b: coalesced float4 copy from Kp
    for (int s4 = tid; s4 < 128 * b; s4 += 256) {
        int bk = (s4 >> 7) + 1;
        int r4 = (s4 & 127) << 2;
        *(float4*)&Sstf[((bk - 1) << 9) + r4] =
            *(const float4*)&Kp[bk * KP_PER_B + l * 512 + r4];
    }
    if (tid < 111) stats[tid] = 0.f;
    if (b == 0) {
        for (int i = tid; i < 4400; i += 256) hT[i] = 0.f;
    }
    __syncthreads();

    switch (b) {
        case 1: layer1<1>(tid, W1b, Sstf, hT); break;
        case 2: layer1<2>(tid, W1b, Sstf, hT); break;
        case 3: layer1<3>(tid, W1b, Sstf, hT); break;
        case 4: layer1<4>(tid, W1b, Sstf, hT); break;
        case 5: layer1<5>(tid, W1b, Sstf, hT); break;
        case 6: layer1<6>(tid, W1b, Sstf, hT); break;
        case 7: layer1<7>(tid, W1b, Sstf, hT); break;
        default: break;
    }
    __syncthreads();

    // gelu(+bias) in place, distributed
    for (int i = tid; i < 4000; i += 256) {
        int row = i / 40;
        int j = i - row * 40;
        hT[row * 44 + j] = gelu_f(hT[row * 44 + j] + bq1[j]);
    }
    __syncthreads();

    float* total_l = stats;
    float* S_l = stats + 10;
    float* lp_acc = stats + 110;

    if (tid < 100) {
        int row = tid;
        float g[40];
        #pragma unroll
        for (int j4 = 0; j4 < 10; ++j4) {
            float4 gv = *(const float4*)&hT[row * 44 + j4 * 4];
            g[j4 * 4 + 0] = gv.x; g[j4 * 4 + 1] = gv.y;
            g[j4 * 4 + 2] = gv.z; g[j4 * 4 + 3] = gv.w;
        }
        float out[10];
        #pragma unroll
        for (int c = 0; c < 10; ++c) out[c] = bq2[c];
        #pragma unroll
        for (int j = 0; j < 40; ++j) {
            float gj = g[j];
            #pragma unroll
            for (int c = 0; c < 10; ++c)
                out[c] = fmaf(gj, Wq2[j * 10 + c], out[c]);
        }
        float m = out[0]; int am = 0;
        #pragma unroll
        for (int c = 1; c < 10; ++c)
            if (out[c] > m) { m = out[c]; am = c; }
        float e[10], s = 0.f;
        #pragma unroll
        for (int c = 0; c < 10; ++c) { e[c] = expf(out[c] - m); s += e[c]; }
        float inv = 1.f / s;
        float cq[10], s1 = 0.f;
        #pragma unroll
        for (int c = 0; c < 10; ++c) { cq[c] = e[c] * inv; s1 += cq[c]; }
        float mean = s1 * 0.1f;
        float var = 0.f;
        #pragma unroll
        for (int c = 0; c < 10; ++c) { float d = cq[c] - mean; var += d * d; }
        float sd = sqrtf(var / 9.f);
        float sp = log1pf(expf(sd));             // softplus(std)
        float lp = -logf(sp) - 0.91893853320467274f;  // ((x-mu)/sigma)^2 ~ 1e-16
        mu_g[bl * 100 + row] = mean;             // contiguous (R9 transpose reverted)
        atomicAdd(lp_acc, lp);
        #pragma unroll
        for (int c = 0; c < 10; ++c) {
            atomicAdd(&total_l[c], cq[c]);
            atomicAdd(&S_l[am * 10 + c], cq[c]);
        }
    }
    __syncthreads();
    if (tid == 0) atomicAdd(&acc_g[0], lp_acc[0]);
    if (tid < 100) {
        centers_g[bl * 100 + tid] = (total_l[tid % 10] - S_l[tid]) * 0.01f;
    }
}

// ------------- kernel 3: fused [proj_back+reshape-sum] ++ [cross-entropy] ---
// Blocks 0..3647: ccs (933888 elements, OUTPUT bf16 -- attn rounded to bf16
// at staging anyway, bit-identical, half the write/read bytes). Blocks
// 3648..3847: ce, 4 wave-units per block. Shift-only ccs index math
// (verified R9): i=J>>6, Jm=J&63, bs=Jm>>3, r2=(Jm&7)*14592+k2d2, ls=r2>>9,
// mm=r2&511 where J=bh*10+i2. ce reads the original mu layout (strided,
// L2-resident -- verified R0-R8).
__global__ void k_ccs_ce(const float* __restrict__ centers_g,
                         const float* __restrict__ Wp, const float* __restrict__ bp,
                         bf16_t* __restrict__ ccs_b,
                         const float* __restrict__ mu_g, float* __restrict__ acc_g,
                         float* __restrict__ outp) {
    int bid = blockIdx.x;
    if (bid < KCCS_BLOCKS) {
        int tid = bid * 256 + threadIdx.x;
        int k2d2 = tid % (LK * DK);
        int bh = tid / (LK * DK);
        float s = 0.f;
        #pragma unroll
        for (int i2 = 0; i2 < 10; ++i2) {
            int J  = bh * 10 + i2;
            int i  = J >> 6;
            int Jm = J & 63;
            int bs = Jm >> 3;
            int r2 = (Jm & 7) * 14592 + k2d2;
            int ls = r2 >> 9;
            int mm = r2 & 511;
            const float* cen = centers_g + (bs * LK + ls) * 100 + i * 10;
            float val = bp[mm];
            #pragma unroll
            for (int c = 0; c < 10; ++c)
                val = fmaf(cen[c], Wp[c * 512 + mm], val);
            s += gelu_f(val);
        }
        ccs_b[tid] = (bf16_t)s;
        return;
    }
    // ---- ce part: unit = (bid-KCCS)*4 + wave ----
    int unit = (bid - KCCS_BLOCKS) * 4 + (threadIdx.x >> 6);
    int b = unit / 100;
    int u = unit % 100;
    int lane = threadIdx.x & 63;
    float v[4];
    #pragma unroll
    for (int t = 0; t < 4; ++t) {
        int l = lane + t * 64;
        v[t] = (l < LK) ? mu_g[(b * LK + l) * 100 + u] : -3.4e38f;
    }
    float m = fmaxf(fmaxf(v[0], v[1]), fmaxf(v[2], v[3]));
    for (int o = 32; o > 0; o >>= 1) m = fmaxf(m, __shfl_xor(m, o, 64));
    float se = 0.f;
    #pragma unroll
    for (int t = 0; t < 4; ++t) {
        int l = lane + t * 64;
        if (l < LK) se += expf(v[t] - m);
    }
    for (int o = 32; o > 0; o >>= 1) se += __shfl_xor(se, o, 64);
    float lse = m + logf(se);
    float dot = 0.f;
    #pragma unroll
    for (int t = 0; t < 4; ++t) {
        int l = lane + t * 64;
        if (l < LK) dot += v[t] * (v[t] - lse);
    }
    for (int o = 32; o > 0; o >>= 1) dot += __shfl_xor(dot, o, 64);
    if (lane == 0) {
        atomicAdd(&acc_g[1], -dot * (1.f / 800.f));
        __threadfence();
        unsigned int old = atomicAdd((unsigned int*)&acc_g[2], 1u);
        if (old == 799u) {
            __threadfence();
            outp[8388608] = -(acc_g[0] * (1.f / (float)NROWS)) + acc_g[1];
        }
    }
}

// ------------- kernel 4: MFMA flash attention (228 keys, chunks of 64) ------
// K (ccs) and V (Vp) now arrive as bf16: staging loads bf16x4 (8B) directly,
// no cvt -- half the staged bytes, bit-identical values. 1/8 scale folded
// into Q staging (power-of-2, exact). launch_bounds (256,4).
#define QT 128
__global__ __launch_bounds__(256, 4) void k_attn(
        const float* __restrict__ Q, const bf16_t* __restrict__ ccs_b,
        const bf16_t* __restrict__ Vpb, float* __restrict__ outp) {
    __shared__ __align__(16) char smem[36864];
    bf16_t* Kl = (bf16_t*)(smem);
    bf16_t* Vt = (bf16_t*)(smem + 9216);
    bf16_t* Pl = (bf16_t*)(smem + 18432);

    int tid = threadIdx.x;
    int wid = tid >> 6;
    int lane = tid & 63;
    int ln = lane & 15;
    int qd = lane >> 4;
    int bid = blockIdx.x;        // 1024
    int bh = bid >> 4;           // b*8+h
    int qt = bid & 15;
    int qbase = qt * QT;

    const float*  Qbh = Q + (size_t)bh * SL * DK;
    const bf16_t* Kbh = ccs_b + (size_t)bh * LK * DK;
    const bf16_t* Vbh = Vpb + (size_t)bh * LK * DK;

    for (int s = tid; s < QT * 32; s += 256) {
        int r = s >> 5;
        int c2 = s & 31;
        float2 v = *(const float2*)&Qbh[(size_t)(qbase + r) * DK + c2 * 2];
        *(bf16x2*)&Pl[r * 72 + c2 * 2] =
            (bf16x2){(bf16_t)(v.x * 0.125f), (bf16_t)(v.y * 0.125f)};
    }
    __syncthreads();
    bf16x8 qf[2][2];
    #pragma unroll
    for (int mt = 0; mt < 2; ++mt)
        #pragma unroll
        for (int ks = 0; ks < 2; ++ks)
            qf[mt][ks] = *(const bf16x8*)&Pl[(wid * 32 + mt * 16 + ln) * 72 + ks * 32 + qd * 8];

    f32x4 acc_o[2][4];
    float mrow[2][4], lrow[2][4];
    #pragma unroll
    for (int mt = 0; mt < 2; ++mt)
        #pragma unroll
        for (int t = 0; t < 4; ++t) {
            acc_o[mt][t] = (f32x4)(0.f);
            mrow[mt][t] = -3.0e38f;
            lrow[mt][t] = 0.f;
        }

    for (int ch = 0; ch < 4; ++ch) {
        int k0 = ch * 64;
        __syncthreads();
        for (int s = tid; s < 64 * 16; s += 256) {
            int kk = s >> 4;
            int c4 = s & 15;
            int key = k0 + kk;
            bf16x4 v = (key < LK) ? *(const bf16x4*)&Kbh[key * DK + c4 * 4]
                                  : (bf16x4)(bf16_t)0.f;
            *(bf16x4*)&Kl[kk * 72 + c4 * 4] = v;
        }
        for (int s = tid; s < 64 * 16; s += 256) {
            int kk = s >> 4;
            int c4 = s & 15;
            int key = k0 + kk;
            bf16x4 v = (key < LK) ? *(const bf16x4*)&Vbh[key * DK + c4 * 4]
                                  : (bf16x4)(bf16_t)0.f;
            Vt[(c4 * 4 + 0) * 72 + kk] = v[0];
            Vt[(c4 * 4 + 1) * 72 + kk] = v[1];
            Vt[(c4 * 4 + 2) * 72 + kk] = v[2];
            Vt[(c4 * 4 + 3) * 72 + kk] = v[3];
        }
        __syncthreads();

        f32x4 accs[2][4];
        #pragma unroll
        for (int mt = 0; mt < 2; ++mt)
            #pragma unroll
            for (int nt = 0; nt < 4; ++nt) accs[mt][nt] = (f32x4)(0.f);
        #pragma unroll
        for (int ks = 0; ks < 2; ++ks) {
            #pragma unroll
            for (int nt = 0; nt < 4; ++nt) {
                bf16x8 bf = *(const bf16x8*)&Kl[(nt * 16 + ln) * 72 + ks * 32 + qd * 8];
                #pragma unroll
                for (int mt = 0; mt < 2; ++mt)
                    accs[mt][nt] = __builtin_amdgcn_mfma_f32_16x16x32_bf16(qf[mt][ks], bf, accs[mt][nt], 0, 0, 0);
            }
        }

        #pragma unroll
        for (int mt = 0; mt < 2; ++mt) {
            #pragma unroll
            for (int r = 0; r < 4; ++r) {
                float sv[4];
                #pragma unroll
                for (int nt = 0; nt < 4; ++nt) {
                    float s = accs[mt][nt][r];
                    int key = k0 + nt * 16 + ln;
                    sv[nt] = (key < LK) ? s : -3.0e38f;
                }
                float rmax = fmaxf(fmaxf(sv[0], sv[1]), fmaxf(sv[2], sv[3]));
                #pragma unroll
                for (int o = 1; o < 16; o <<= 1)
                    rmax = fmaxf(rmax, __shfl_xor(rmax, o, 64));
                float mold = mrow[mt][r];
                float mnew = fmaxf(mold, rmax);
                float alpha = __expf(mold - mnew);
                float p[4], psum = 0.f;
                #pragma unroll
                for (int nt = 0; nt < 4; ++nt) {
                    p[nt] = __expf(sv[nt] - mnew);
                    psum += p[nt];
                }
                #pragma unroll
                for (int o = 1; o < 16; o <<= 1)
                    psum += __shfl_xor(psum, o, 64);
                lrow[mt][r] = lrow[mt][r] * alpha + psum;
                mrow[mt][r] = mnew;
                #pragma unroll
                for (int ntv = 0; ntv < 4; ++ntv)
                    acc_o[mt][ntv][r] *= alpha;
                int prow = (wid * 32 + mt * 16 + qd * 4 + r) * 72;
                #pragma unroll
                for (int nt = 0; nt < 4; ++nt)
                    Pl[prow + nt * 16 + ln] = (bf16_t)p[nt];
            }
        }

        #pragma unroll
        for (int ks = 0; ks < 2; ++ks) {
            bf16x8 pa[2];
            #pragma unroll
            for (int mt = 0; mt < 2; ++mt)
                pa[mt] = *(const bf16x8*)&Pl[(wid * 32 + mt * 16 + ln) * 72 + ks * 32 + qd * 8];
            #pragma unroll
            for (int ntv = 0; ntv < 4; ++ntv) {
                bf16x8 vb = *(const bf16x8*)&Vt[(ntv * 16 + ln) * 72 + ks * 32 + qd * 8];
                #pragma unroll
                for (int mt = 0; mt < 2; ++mt)
                    acc_o[mt][ntv] = __builtin_amdgcn_mfma_f32_16x16x32_bf16(pa[mt], vb, acc_o[mt][ntv], 0, 0, 0);
            }
        }
    }

    #pragma unroll
    for (int mt = 0; mt < 2; ++mt) {
        #pragma unroll
        for (int r = 0; r < 4; ++r) {
            float inv = 1.f / lrow[mt][r];
            int q_idx = qbase + wid * 32 + mt * 16 + qd * 4 + r;
            float* orow = outp + ((size_t)bh * SL + q_idx) * DK;
            #pragma unroll
            for (int ntv = 0; ntv < 4; ++ntv)
                orow[ntv * 16 + ln] = acc_o[mt][ntv][r] * inv;
        }
    }
}

extern "C" void kernel_launch(void* const* d_in, const int* in_sizes, int n_in,
                              void* d_out, int out_size, void* d_ws, size_t ws_size,
                              hipStream_t stream) {
    const float* Q   = (const float*)d_in[0];
    const float* K   = (const float*)d_in[1];
    const float* V   = (const float*)d_in[2];
    const float* Wq1 = (const float*)d_in[7];
    const float* bq1 = (const float*)d_in[8];
    const float* Wq2 = (const float*)d_in[9];
    const float* bq2 = (const float*)d_in[10];
    const float* Wp  = (const float*)d_in[11];
    const float* bp  = (const float*)d_in[12];
    float* out = (float*)d_out;

    float* ws      = (float*)d_ws;
    float* Kp      = ws;                 // 933888 f32
    bf16_t* Vpb    = (bf16_t*)(ws + 933888);   // 933888 bf16 (uses half the slot)
    float* mu      = ws + 1867776;       // 182400
    float* centers = ws + 2050176;       // 182400
    bf16_t* ccsb   = (bf16_t*)(ws + 2232576);  // 933888 bf16
    float* acc     = ws + 3166464;       // 4 (acc[2] doubles as uint counter)
    bf16_t* W1b    = (bf16_t*)(ws + 3166468);  // 512*40 bf16 = 40960 B

    // pool (+ W1 prep + acc init) -> mlp -> [ccs ++ ce(+final)] -> attn
    k_pool<<<POOL2_BLOCKS + 80, 256, 0, stream>>>(K, V, Kp, Vpb, Wq1, W1b, acc);
    k_mlp<<<NB * LK, 256, 0, stream>>>(Kp, W1b, bq1, Wq2, bq2, mu, centers, acc);
    k_ccs_ce<<<KCCS_BLOCKS + KCE_BLOCKS, 256, 0, stream>>>(centers, Wp, bp, ccsb,
                                                           mu, acc, out);
    k_attn<<<NB * NH * (SL / QT), 256, 0, stream>>>(Q, ccsb, Vpb, out);
}

// Round 11
// 319.852 us; speedup vs baseline: 1.5090x; 1.0025x over previous
//
#include <hip/hip_runtime.h>
#include <math.h>

#define NCL 10
#define DM 512
#define NH 8
#define DK 64
#define NB 8
#define SL 2048
#define LK 228
#define UF 100
#define KP_PER_B (NH*LK*DK)     // 116736
#define KP_TOT (NB*KP_PER_B)    // 933888
#define NROWS (NB*LK*UF)        // 182400
#define POOL2_BLOCKS 8192       // 2*NB*DM channels, one per block
#define KCCS_BLOCKS 3648        // KP_TOT/256
#define KCE_BLOCKS 200          // 800 (b,u) units, 4 per block

typedef __bf16 bf16_t;
typedef __attribute__((ext_vector_type(2))) __bf16 bf16x2;
typedef __attribute__((ext_vector_type(4))) __bf16 bf16x4;
typedef __attribute__((ext_vector_type(8))) __bf16 bf16x8;
typedef __attribute__((ext_vector_type(4))) float f32x4;

__device__ __forceinline__ float gelu_f(float x) {
    return 0.5f * x * (1.f + erff(x * 0.70710678118654752f));
}

// ------------- kernel 1: max-pool K,V, LDS-staged coalesced ------------------
// One block per (kv, b, c) channel; stage 2048-float row via float4, max from
// LDS (stride 9 coprime to 32 banks -> conflict-free). K path writes f32 Kp
// (mlp needs f32); V path writes bf16 Vp (attn rounds to bf16 anyway ->
// bit-identical, half the bytes). Tail: W1 bf16 prep + acc init.
__global__ void k_pool(const float* __restrict__ K, const float* __restrict__ V,
                       float* __restrict__ Kp, bf16_t* __restrict__ Vpb,
                       const float* __restrict__ Wq1, bf16_t* __restrict__ W1b,
                       float* __restrict__ acc) {
    int bid = blockIdx.x;
    int tid = threadIdx.x;
    if (bid >= POOL2_BLOCKS) {
        int i = (bid - POOL2_BLOCKS) * 256 + tid;
        if (i < 512 * 40) W1b[i] = (bf16_t)Wq1[i];
        if (bid == POOL2_BLOCKS && tid < 4) acc[tid] = 0.f;
        return;
    }
    int kv = bid >> 12;          // 0 = K, 1 = V
    int e0 = bid & 4095;         // b*512 + c
    int b = e0 >> 9;
    int c = e0 & 511;
    const float* src = kv ? V : K;
    __shared__ float buf[2048];
    const float* base = src + (size_t)e0 * 2048;
    #pragma unroll
    for (int i = 0; i < 2; ++i) {
        int i4 = (tid + i * 256) << 2;
        *(float4*)&buf[i4] = *(const float4*)&base[i4];
    }
    __syncthreads();
    if (tid < LK) {
        int p0 = tid * 9 - 4;
        float mx = -3.4e38f;
        #pragma unroll
        for (int j = 0; j < 9; ++j) {
            int p = p0 + j;
            if (p >= 0 && p < 2048) mx = fmaxf(mx, buf[p]);
        }
        int e = b * KP_PER_B + c * LK + tid;
        if (kv) Vpb[e] = (bf16_t)mx;
        else    Kp[e]  = mx;
    }
}

// ------------- kernel 2: sparse q-MLP, b-specialized unrolled layer 1 --------
// R5-verified inner stream, TWO deliberate changes this round:
//  (a) b-interleave REVERTED (b=bl/LK): R8/R10 showed it doubles FETCH
//      (3.4->6.6MB, lost Kp L2 sharing between consecutive-l blocks) and
//      drifted dur 98.5->103.5. Back to the proven R5 mapping.
//  (b) k-loop `#pragma unroll 1` -> full unroll: interleaves the two virtual
//      threads' bodies in one stream -> 2x independent W1b loads in flight
//      per wave (at VGPR 44 only ~3 were in flight; both passes' L2
//      latencies previously ADDED). Est. VGPR ~80-95 < 128 cap -- no spill.
//      Failure signature if wrong: WRITE_SIZE >> 2MB -> revert.
// LDS: Sstf f32[7][512] @0 (14336) | hT f32[100][44] @14336 (17600) |
//      stats f32[111] @31936 -> 32384 B.
template<int B>
__device__ __forceinline__ void layer1(int tid, const bf16_t* __restrict__ W1b,
                                       const float* __restrict__ Sstf,
                                       float* __restrict__ hT) {
    #pragma unroll
    for (int k = 0; k < 2; ++k) {
        int vt = tid + (k << 8);
        if (vt < 500) {
            int m = vt / 5;
            int h8 = vt - m * 5;            // 0..4 -> cols h8*8..h8*8+7
            int bm = (12 * m) % 100;
            float h[8];
            #pragma unroll
            for (int i = 0; i < 8; ++i) h[i] = 0.f;
            #pragma unroll
            for (int s = 1; s <= B; ++s) {
                const int t = 99 - B + s;
                int d0 = t - bm; if (d0 < 0) d0 += 100;
                int r0 = ((m << 9) + d0 - t) / 100;   // exact division
                const float* srow = &Sstf[(s - 1) << 9];
                #pragma unroll
                for (int j = 0; j < 6; ++j) {
                    int c = d0 + j * 100;
                    if (j < 5 || c < 512) {
                        float v = srow[r0 + j];
                        bf16x8 w = *(const bf16x8*)&W1b[c * 40 + h8 * 8];
                        #pragma unroll
                        for (int i = 0; i < 8; ++i)
                            h[i] = fmaf(v, (float)w[i], h[i]);
                    }
                }
            }
            #pragma unroll
            for (int i = 0; i < 8; ++i) hT[m * 44 + h8 * 8 + i] = h[i];
        }
    }
}

__global__ __launch_bounds__(256, 4) void k_mlp(
        const float* __restrict__ Kp, const bf16_t* __restrict__ W1b,
        const float* __restrict__ bq1,
        const float* __restrict__ Wq2, const float* __restrict__ bq2,
        float* __restrict__ mu_g, float* __restrict__ centers_g,
        float* __restrict__ acc_g) {
    __shared__ __align__(16) char smem[32384];
    float* Sstf  = (float*)smem;                 // [7][512], row (bk-1)
    float* hT    = (float*)(smem + 14336);       // [100][44]
    float* stats = (float*)(smem + 31936);       // [0..9]=total [10..109]=S [110]=lp

    int tid = threadIdx.x;
    int bl = blockIdx.x;          // 0..1823 (R5 mapping: L2-friendly)
    int b = bl / LK;
    int l = bl % LK;

    // stage Sstf rows for bk=1..b: coalesced float4 copy from Kp
    for (int s4 = tid; s4 < 128 * b; s4 += 256) {
        int bk = (s4 >> 7) + 1;
        int r4 = (s4 & 127) << 2;
        *(float4*)&Sstf[((bk - 1) << 9) + r4] =
            *(const float4*)&Kp[bk * KP_PER_B + l * 512 + r4];
    }
    if (tid < 111) stats[tid] = 0.f;
    if (b == 0) {
        for (int i = tid; i < 4400; i += 256) hT[i] = 0.f;
    }
    __syncthreads();

    switch (b) {
        case 1: layer1<1>(tid, W1b, Sstf, hT); break;
        case 2: layer1<2>(tid, W1b, Sstf, hT); break;
        case 3: layer1<3>(tid, W1b, Sstf, hT); break;
        case 4: layer1<4>(tid, W1b, Sstf, hT); break;
        case 5: layer1<5>(tid, W1b, Sstf, hT); break;
        case 6: layer1<6>(tid, W1b, Sstf, hT); break;
        case 7: layer1<7>(tid, W1b, Sstf, hT); break;
        default: break;
    }
    __syncthreads();

    // gelu(+bias) in place, distributed
    for (int i = tid; i < 4000; i += 256) {
        int row = i / 40;
        int j = i - row * 40;
        hT[row * 44 + j] = gelu_f(hT[row * 44 + j] + bq1[j]);
    }
    __syncthreads();

    float* total_l = stats;
    float* S_l = stats + 10;
    float* lp_acc = stats + 110;

    if (tid < 100) {
        int row = tid;
        float g[40];
        #pragma unroll
        for (int j4 = 0; j4 < 10; ++j4) {
            float4 gv = *(const float4*)&hT[row * 44 + j4 * 4];
            g[j4 * 4 + 0] = gv.x; g[j4 * 4 + 1] = gv.y;
            g[j4 * 4 + 2] = gv.z; g[j4 * 4 + 3] = gv.w;
        }
        float out[10];
        #pragma unroll
        for (int c = 0; c < 10; ++c) out[c] = bq2[c];
        #pragma unroll
        for (int j = 0; j < 40; ++j) {
            float gj = g[j];
            #pragma unroll
            for (int c = 0; c < 10; ++c)
                out[c] = fmaf(gj, Wq2[j * 10 + c], out[c]);
        }
        float m = out[0]; int am = 0;
        #pragma unroll
        for (int c = 1; c < 10; ++c)
            if (out[c] > m) { m = out[c]; am = c; }
        float e[10], s = 0.f;
        #pragma unroll
        for (int c = 0; c < 10; ++c) { e[c] = expf(out[c] - m); s += e[c]; }
        float inv = 1.f / s;
        float cq[10], s1 = 0.f;
        #pragma unroll
        for (int c = 0; c < 10; ++c) { cq[c] = e[c] * inv; s1 += cq[c]; }
        float mean = s1 * 0.1f;
        float var = 0.f;
        #pragma unroll
        for (int c = 0; c < 10; ++c) { float d = cq[c] - mean; var += d * d; }
        float sd = sqrtf(var / 9.f);
        float sp = log1pf(expf(sd));             // softplus(std)
        float lp = -logf(sp) - 0.91893853320467274f;  // ((x-mu)/sigma)^2 ~ 1e-16
        mu_g[bl * 100 + row] = mean;
        atomicAdd(lp_acc, lp);
        #pragma unroll
        for (int c = 0; c < 10; ++c) {
            atomicAdd(&total_l[c], cq[c]);
            atomicAdd(&S_l[am * 10 + c], cq[c]);
        }
    }
    __syncthreads();
    if (tid == 0) atomicAdd(&acc_g[0], lp_acc[0]);
    if (tid < 100) {
        centers_g[bl * 100 + tid] = (total_l[tid % 10] - S_l[tid]) * 0.01f;
    }
}

// ------------- kernel 3: fused [proj_back+reshape-sum] ++ [cross-entropy] ---
// Blocks 0..3647: ccs (bf16 output). Blocks 3648..3847: ce, 4 wave-units per
// block. Shift-only ccs index math (verified R9). ce reads strided mu
// (L2-resident, verified R0-R8).
__global__ void k_ccs_ce(const float* __restrict__ centers_g,
                         const float* __restrict__ Wp, const float* __restrict__ bp,
                         bf16_t* __restrict__ ccs_b,
                         const float* __restrict__ mu_g, float* __restrict__ acc_g,
                         float* __restrict__ outp) {
    int bid = blockIdx.x;
    if (bid < KCCS_BLOCKS) {
        int tid = bid * 256 + threadIdx.x;
        int k2d2 = tid % (LK * DK);
        int bh = tid / (LK * DK);
        float s = 0.f;
        #pragma unroll
        for (int i2 = 0; i2 < 10; ++i2) {
            int J  = bh * 10 + i2;
            int i  = J >> 6;
            int Jm = J & 63;
            int bs = Jm >> 3;
            int r2 = (Jm & 7) * 14592 + k2d2;
            int ls = r2 >> 9;
            int mm = r2 & 511;
            const float* cen = centers_g + (bs * LK + ls) * 100 + i * 10;
            float val = bp[mm];
            #pragma unroll
            for (int c = 0; c < 10; ++c)
                val = fmaf(cen[c], Wp[c * 512 + mm], val);
            s += gelu_f(val);
        }
        ccs_b[tid] = (bf16_t)s;
        return;
    }
    // ---- ce part: unit = (bid-KCCS)*4 + wave ----
    int unit = (bid - KCCS_BLOCKS) * 4 + (threadIdx.x >> 6);
    int b = unit / 100;
    int u = unit % 100;
    int lane = threadIdx.x & 63;
    float v[4];
    #pragma unroll
    for (int t = 0; t < 4; ++t) {
        int l = lane + t * 64;
        v[t] = (l < LK) ? mu_g[(b * LK + l) * 100 + u] : -3.4e38f;
    }
    float m = fmaxf(fmaxf(v[0], v[1]), fmaxf(v[2], v[3]));
    for (int o = 32; o > 0; o >>= 1) m = fmaxf(m, __shfl_xor(m, o, 64));
    float se = 0.f;
    #pragma unroll
    for (int t = 0; t < 4; ++t) {
        int l = lane + t * 64;
        if (l < LK) se += expf(v[t] - m);
    }
    for (int o = 32; o > 0; o >>= 1) se += __shfl_xor(se, o, 64);
    float lse = m + logf(se);
    float dot = 0.f;
    #pragma unroll
    for (int t = 0; t < 4; ++t) {
        int l = lane + t * 64;
        if (l < LK) dot += v[t] * (v[t] - lse);
    }
    for (int o = 32; o > 0; o >>= 1) dot += __shfl_xor(dot, o, 64);
    if (lane == 0) {
        atomicAdd(&acc_g[1], -dot * (1.f / 800.f));
        __threadfence();
        unsigned int old = atomicAdd((unsigned int*)&acc_g[2], 1u);
        if (old == 799u) {
            __threadfence();
            outp[8388608] = -(acc_g[0] * (1.f / (float)NROWS)) + acc_g[1];
        }
    }
}

// ------------- kernel 4: MFMA flash attention (228 keys, chunks of 64) ------
// K (ccs) and V (Vp) arrive as bf16: bf16x4 staging, no cvt. 1/8 scale folded
// into Q staging (power-of-2, exact). launch_bounds (256,4).
#define QT 128
__global__ __launch_bounds__(256, 4) void k_attn(
        const float* __restrict__ Q, const bf16_t* __restrict__ ccs_b,
        const bf16_t* __restrict__ Vpb, float* __restrict__ outp) {
    __shared__ __align__(16) char smem[36864];
    bf16_t* Kl = (bf16_t*)(smem);
    bf16_t* Vt = (bf16_t*)(smem + 9216);
    bf16_t* Pl = (bf16_t*)(smem + 18432);

    int tid = threadIdx.x;
    int wid = tid >> 6;
    int lane = tid & 63;
    int ln = lane & 15;
    int qd = lane >> 4;
    int bid = blockIdx.x;        // 1024
    int bh = bid >> 4;           // b*8+h
    int qt = bid & 15;
    int qbase = qt * QT;

    const float*  Qbh = Q + (size_t)bh * SL * DK;
    const bf16_t* Kbh = ccs_b + (size_t)bh * LK * DK;
    const bf16_t* Vbh = Vpb + (size_t)bh * LK * DK;

    for (int s = tid; s < QT * 32; s += 256) {
        int r = s >> 5;
        int c2 = s & 31;
        float2 v = *(const float2*)&Qbh[(size_t)(qbase + r) * DK + c2 * 2];
        *(bf16x2*)&Pl[r * 72 + c2 * 2] =
            (bf16x2){(bf16_t)(v.x * 0.125f), (bf16_t)(v.y * 0.125f)};
    }
    __syncthreads();
    bf16x8 qf[2][2];
    #pragma unroll
    for (int mt = 0; mt < 2; ++mt)
        #pragma unroll
        for (int ks = 0; ks < 2; ++ks)
            qf[mt][ks] = *(const bf16x8*)&Pl[(wid * 32 + mt * 16 + ln) * 72 + ks * 32 + qd * 8];

    f32x4 acc_o[2][4];
    float mrow[2][4], lrow[2][4];
    #pragma unroll
    for (int mt = 0; mt < 2; ++mt)
        #pragma unroll
        for (int t = 0; t < 4; ++t) {
            acc_o[mt][t] = (f32x4)(0.f);
            mrow[mt][t] = -3.0e38f;
            lrow[mt][t] = 0.f;
        }

    for (int ch = 0; ch < 4; ++ch) {
        int k0 = ch * 64;
        __syncthreads();
        for (int s = tid; s < 64 * 16; s += 256) {
            int kk = s >> 4;
            int c4 = s & 15;
            int key = k0 + kk;
            bf16x4 v = (key < LK) ? *(const bf16x4*)&Kbh[key * DK + c4 * 4]
                                  : (bf16x4)(bf16_t)0.f;
            *(bf16x4*)&Kl[kk * 72 + c4 * 4] = v;
        }
        for (int s = tid; s < 64 * 16; s += 256) {
            int kk = s >> 4;
            int c4 = s & 15;
            int key = k0 + kk;
            bf16x4 v = (key < LK) ? *(const bf16x4*)&Vbh[key * DK + c4 * 4]
                                  : (bf16x4)(bf16_t)0.f;
            Vt[(c4 * 4 + 0) * 72 + kk] = v[0];
            Vt[(c4 * 4 + 1) * 72 + kk] = v[1];
            Vt[(c4 * 4 + 2) * 72 + kk] = v[2];
            Vt[(c4 * 4 + 3) * 72 + kk] = v[3];
        }
        __syncthreads();

        f32x4 accs[2][4];
        #pragma unroll
        for (int mt = 0; mt < 2; ++mt)
            #pragma unroll
            for (int nt = 0; nt < 4; ++nt) accs[mt][nt] = (f32x4)(0.f);
        #pragma unroll
        for (int ks = 0; ks < 2; ++ks) {
            #pragma unroll
            for (int nt = 0; nt < 4; ++nt) {
                bf16x8 bf = *(const bf16x8*)&Kl[(nt * 16 + ln) * 72 + ks * 32 + qd * 8];
                #pragma unroll
                for (int mt = 0; mt < 2; ++mt)
                    accs[mt][nt] = __builtin_amdgcn_mfma_f32_16x16x32_bf16(qf[mt][ks], bf, accs[mt][nt], 0, 0, 0);
            }
        }

        #pragma unroll
        for (int mt = 0; mt < 2; ++mt) {
            #pragma unroll
            for (int r = 0; r < 4; ++r) {
                float sv[4];
                #pragma unroll
                for (int nt = 0; nt < 4; ++nt) {
                    float s = accs[mt][nt][r];
                    int key = k0 + nt * 16 + ln;
                    sv[nt] = (key < LK) ? s : -3.0e38f;
                }
                float rmax = fmaxf(fmaxf(sv[0], sv[1]), fmaxf(sv[2], sv[3]));
                #pragma unroll
                for (int o = 1; o < 16; o <<= 1)
                    rmax = fmaxf(rmax, __shfl_xor(rmax, o, 64));
                float mold = mrow[mt][r];
                float mnew = fmaxf(mold, rmax);
                float alpha = __expf(mold - mnew);
                float p[4], psum = 0.f;
                #pragma unroll
                for (int nt = 0; nt < 4; ++nt) {
                    p[nt] = __expf(sv[nt] - mnew);
                    psum += p[nt];
                }
                #pragma unroll
                for (int o = 1; o < 16; o <<= 1)
                    psum += __shfl_xor(psum, o, 64);
                lrow[mt][r] = lrow[mt][r] * alpha + psum;
                mrow[mt][r] = mnew;
                #pragma unroll
                for (int ntv = 0; ntv < 4; ++ntv)
                    acc_o[mt][ntv][r] *= alpha;
                int prow = (wid * 32 + mt * 16 + qd * 4 + r) * 72;
                #pragma unroll
                for (int nt = 0; nt < 4; ++nt)
                    Pl[prow + nt * 16 + ln] = (bf16_t)p[nt];
            }
        }

        #pragma unroll
        for (int ks = 0; ks < 2; ++ks) {
            bf16x8 pa[2];
            #pragma unroll
            for (int mt = 0; mt < 2; ++mt)
                pa[mt] = *(const bf16x8*)&Pl[(wid * 32 + mt * 16 + ln) * 72 + ks * 32 + qd * 8];
            #pragma unroll
            for (int ntv = 0; ntv < 4; ++ntv) {
                bf16x8 vb = *(const bf16x8*)&Vt[(ntv * 16 + ln) * 72 + ks * 32 + qd * 8];
                #pragma unroll
                for (int mt = 0; mt < 2; ++mt)
                    acc_o[mt][ntv] = __builtin_amdgcn_mfma_f32_16x16x32_bf16(pa[mt], vb, acc_o[mt][ntv], 0, 0, 0);
            }
        }
    }

    #pragma unroll
    for (int mt = 0; mt < 2; ++mt) {
        #pragma unroll
        for (int r = 0; r < 4; ++r) {
            float inv = 1.f / lrow[mt][r];
            int q_idx = qbase + wid * 32 + mt * 16 + qd * 4 + r;
            float* orow = outp + ((size_t)bh * SL + q_idx) * DK;
            #pragma unroll
            for (int ntv = 0; ntv < 4; ++ntv)
                orow[ntv * 16 + ln] = acc_o[mt][ntv][r] * inv;
        }
    }
}

extern "C" void kernel_launch(void* const* d_in, const int* in_sizes, int n_in,
                              void* d_out, int out_size, void* d_ws, size_t ws_size,
                              hipStream_t stream) {
    const float* Q   = (const float*)d_in[0];
    const float* K   = (const float*)d_in[1];
    const float* V   = (const float*)d_in[2];
    const float* Wq1 = (const float*)d_in[7];
    const float* bq1 = (const float*)d_in[8];
    const float* Wq2 = (const float*)d_in[9];
    const float* bq2 = (const float*)d_in[10];
    const float* Wp  = (const float*)d_in[11];
    const float* bp  = (const float*)d_in[12];
    float* out = (float*)d_out;

    float* ws      = (float*)d_ws;
    float* Kp      = ws;                 // 933888 f32
    bf16_t* Vpb    = (bf16_t*)(ws + 933888);   // 933888 bf16
    float* mu      = ws + 1867776;       // 182400
    float* centers = ws + 2050176;       // 182400
    bf16_t* ccsb   = (bf16_t*)(ws + 2232576);  // 933888 bf16
    float* acc     = ws + 3166464;       // 4 (acc[2] doubles as uint counter)
    bf16_t* W1b    = (bf16_t*)(ws + 3166468);  // 512*40 bf16 = 40960 B

    // pool (+ W1 prep + acc init) -> mlp -> [ccs ++ ce(+final)] -> attn
    k_pool<<<POOL2_BLOCKS + 80, 256, 0, stream>>>(K, V, Kp, Vpb, Wq1, W1b, acc);
    k_mlp<<<NB * LK, 256, 0, stream>>>(Kp, W1b, bq1, Wq2, bq2, mu, centers, acc);
    k_ccs_ce<<<KCCS_BLOCKS + KCE_BLOCKS, 256, 0, stream>>>(centers, Wp, bp, ccsb,
                                                           mu, acc, out);
    k_attn<<<NB * NH * (SL / QT), 256, 0, stream>>>(Q, ccsb, Vpb, out);
}